// Round 5
// baseline (1328.346 us; speedup 1.0000x reference)
//
#include <hip/hip_runtime.h>

#define I_DIM 1025
#define J_DIM 2048
#define K_B 8
#define NCH 32           // i-chunks for V partials (33 i's each)
#define CHI 33
#define EPSF 1e-20f

// ---------------- helpers ----------------

template<int NV>
__device__ __forceinline__ void shflReduce(float* v) {
  #pragma unroll
  for (int off = 32; off > 0; off >>= 1) {
    #pragma unroll
    for (int q = 0; q < NV; ++q) v[q] += __shfl_down(v[q], off);
  }
}

__device__ __forceinline__ float2 cmul(float2 a, float2 b) {
  return make_float2(a.x*b.x - a.y*b.y, a.x*b.y + a.y*b.x);
}
__device__ __forceinline__ float2 cadd(float2 a, float2 b) {
  return make_float2(a.x + b.x, a.y + b.y);
}
__device__ __forceinline__ float2 csub(float2 a, float2 b) {
  return make_float2(a.x - b.x, a.y - b.y);
}
__device__ __forceinline__ float2 cdiv(float2 a, float2 b) {
  float s = 1.0f / (b.x*b.x + b.y*b.y);
  return make_float2((a.x*b.x + a.y*b.y)*s, (a.y*b.x - a.x*b.y)*s);
}

// ---------------- transpose X -> Xq[i][j]=(re0,im0,re1,im1), + init T/V/W/ctr
// T layout: [n][i][k]; V layout: [n][k][j] (scalar); W: [i][n][m][c]
__global__ __launch_bounds__(256) void k_tr_init(
    const float* __restrict__ X, float4* __restrict__ Xq,
    const float* __restrict__ T0, const float* __restrict__ V0,
    float* __restrict__ T, float* __restrict__ V, float* __restrict__ W,
    unsigned int* __restrict__ ctr)
{
  const int tx = threadIdx.x, ty = threadIdx.y;  // (32, 8)
  const int lt = ty * 32 + tx;
  const int bid = blockIdx.y * 33 + blockIdx.x;
  // ---- init part (first 128 linear blocks) ----
  int t = bid * 256 + lt;
  if (t < 2 * K_B * J_DIM) {               // V: 32768
    int n = t / (K_B * J_DIM);
    int r = t % (K_B * J_DIM);
    int k = r / J_DIM, j = r % J_DIM;
    V[t] = V0[(k * J_DIM + j) * 2 + n];
  }
  if (t < 2 * I_DIM * K_B) {               // T: 16400
    int n = t / (I_DIM * K_B);
    int r = t % (I_DIM * K_B);
    int i = r / K_B, k = r % K_B;
    T[t] = T0[(i * K_B + k) * 2 + n];
  }
  if (t < I_DIM * 8) {                     // W: 8200
    int u = t & 7;
    int c = u & 1, m = (u >> 1) & 1, n = u >> 2;
    W[t] = (n == m && c == 0) ? 1.0f : 0.0f;
  }
  if (t < 8) ctr[t] = 0u;
  // ---- transpose part ----
  __shared__ float t0r[32][33], t0i[32][33], t1r[32][33], t1i[32][33];
  const int i0 = blockIdx.x * 32, j0 = blockIdx.y * 32;
  const float2* __restrict__ X2 = (const float2*)X;
  #pragma unroll
  for (int jj = 0; jj < 4; ++jj) {
    int jl = ty + jj * 8;
    int i = i0 + tx;
    if (i < I_DIM) {
      float2 v0 = X2[(size_t)(0 * J_DIM + j0 + jl) * I_DIM + i];
      float2 v1 = X2[(size_t)(1 * J_DIM + j0 + jl) * I_DIM + i];
      t0r[jl][tx] = v0.x; t0i[jl][tx] = v0.y;
      t1r[jl][tx] = v1.x; t1i[jl][tx] = v1.y;
    }
  }
  __syncthreads();
  #pragma unroll
  for (int ii = 0; ii < 4; ++ii) {
    int il = ty + ii * 8;
    int i = i0 + il;
    if (i < I_DIM) {
      Xq[(size_t)i * J_DIM + j0 + tx] =
        make_float4(t0r[tx][il], t0i[tx][il], t1r[tx][il], t1i[tx][il]);
    }
  }
}

// ---------------- NMF T-step body: upfront X loads, lane-contiguous ----------
template<int N>
__device__ __forceinline__ void nmfT_body(
    int i, int tid,
    const float4* __restrict__ Xq,
    float* __restrict__ T, const float* __restrict__ V,
    const float* __restrict__ W, float* __restrict__ YdR)
{
  // issue all 8 X loads first: 8 independent 16B/lane loads in flight
  float4 xs[8];
  #pragma unroll
  for (int u = 0; u < 8; ++u) xs[u] = Xq[(size_t)i * J_DIM + u * 256 + tid];

  const float4 w = ((const float4*)W)[i * 2 + N];
  float t[K_B];
  const int trow = (N * I_DIM + i) * K_B;
  #pragma unroll
  for (int k = 0; k < K_B; ++k) t[k] = T[trow + k];

  float num[K_B], den[K_B];
  #pragma unroll
  for (int k = 0; k < K_B; ++k) { num[k] = 0.f; den[k] = 0.f; }

  #pragma unroll
  for (int u = 0; u < 8; ++u) {
    int j = u * 256 + tid;
    float v[K_B];
    float rn = 0.f;
    #pragma unroll
    for (int k = 0; k < K_B; ++k) {
      v[k] = V[(N * K_B + k) * J_DIM + j];
      rn += t[k] * v[k];
    }
    float4 x = xs[u];
    float yr = w.x * x.x - w.y * x.y + w.z * x.z - w.w * x.w;
    float yi = w.x * x.y + w.y * x.x + w.z * x.w + w.w * x.z;
    float rd = 1.0f / (fabsf(rn) + EPSF);
    float ydr = (yr * yr + yi * yi) * rd * rd;
    YdR[(size_t)i * J_DIM + j] = ydr;
    #pragma unroll
    for (int k = 0; k < K_B; ++k) { num[k] += ydr * v[k]; den[k] += rd * v[k]; }
  }

  float vals[16];
  #pragma unroll
  for (int k = 0; k < K_B; ++k) { vals[k] = num[k]; vals[K_B + k] = den[k]; }
  shflReduce<16>(vals);
  __shared__ float redT[4][16];
  int wave = tid >> 6, lane = tid & 63;
  if (lane == 0) {
    #pragma unroll
    for (int q = 0; q < 16; ++q) redT[wave][q] = vals[q];
  }
  __syncthreads();
  if (tid < K_B) {
    float nm = redT[0][tid] + redT[1][tid] + redT[2][tid] + redT[3][tid];
    float dn = redT[0][tid + 8] + redT[1][tid + 8] + redT[2][tid + 8] + redT[3][tid + 8];
    T[trow + tid] *= sqrtf(nm / (dn + EPSF));
  }
}

// ---------------- 2x2 solve epilogue (one thread) ----------------------------
template<int N>
__device__ __forceinline__ void ip_solve(
    int i, float D00, float p, float q, float D11, float* __restrict__ W)
{
  D00 += EPSF; D11 += EPSF;
  float2 D01 = make_float2(p, q);
  float2 D10 = make_float2(p, -q);
  float4 w0 = ((const float4*)W)[i * 2 + 0];
  float4 w1 = ((const float4*)W)[i * 2 + 1];
  float2 W00 = make_float2(w0.x, w0.y), W01 = make_float2(w0.z, w0.w);
  float2 W10 = make_float2(w1.x, w1.y), W11 = make_float2(w1.z, w1.w);
  float2 A00 = cadd(make_float2(W00.x * D00, W00.y * D00), cmul(W01, D10));
  float2 A01 = cadd(cmul(W00, D01), make_float2(W01.x * D11, W01.y * D11));
  float2 A10 = cadd(make_float2(W10.x * D00, W10.y * D00), cmul(W11, D10));
  float2 A11 = cadd(cmul(W10, D01), make_float2(W11.x * D11, W11.y * D11));
  float2 det = csub(cmul(A00, A11), cmul(A01, A10));
  float2 b0, b1;
  if (N == 0) {
    b0 = cdiv(A11, det);
    b1 = cdiv(make_float2(-A10.x, -A10.y), det);
  } else {
    b0 = cdiv(make_float2(-A01.x, -A01.y), det);
    b1 = cdiv(A00, det);
  }
  float2 Db0 = cadd(make_float2(D00 * b0.x, D00 * b0.y), cmul(D01, b1));
  float2 Db1 = cadd(cmul(D10, b0), make_float2(D11 * b1.x, D11 * b1.y));
  float ip = b0.x * Db0.x + b0.y * Db0.y + b1.x * Db1.x + b1.y * Db1.y;
  float inv = 1.0f / sqrtf(ip + EPSF);
  ((float4*)W)[i * 2 + N] = make_float4(b0.x * inv, -b0.y * inv, b1.x * inv, -b1.y * inv);
}

// ---------------- IP body: upfront X loads, lane-contiguous ------------------
template<int N>
__device__ __forceinline__ void ip_body(
    int i, int tid,
    const float4* __restrict__ Xq,
    const float* __restrict__ T, const float* __restrict__ V,
    float* __restrict__ W)
{
  float4 xs[8];
  #pragma unroll
  for (int u = 0; u < 8; ++u) xs[u] = Xq[(size_t)i * J_DIM + u * 256 + tid];

  float t[K_B];
  const int trow = (N * I_DIM + i) * K_B;
  #pragma unroll
  for (int k = 0; k < K_B; ++k) t[k] = T[trow + k];

  float d00 = 0.f, d01r = 0.f, d01i = 0.f, d11 = 0.f;
  #pragma unroll
  for (int u = 0; u < 8; ++u) {
    int j = u * 256 + tid;
    float rn = 0.f;
    #pragma unroll
    for (int k = 0; k < K_B; ++k) rn += t[k] * V[(N * K_B + k) * J_DIM + j];
    float wgt = 1.0f / (rn + EPSF);   // reference: 1/(Rn + IP_EPS), no abs
    float4 x = xs[u];
    d00 += (x.x * x.x + x.y * x.y) * wgt;
    d11 += (x.z * x.z + x.w * x.w) * wgt;
    d01r += (x.x * x.z + x.y * x.w) * wgt;
    d01i += (x.y * x.z - x.x * x.w) * wgt;
  }
  float vals[4] = {d00, d01r, d01i, d11};
  shflReduce<4>(vals);
  __shared__ float redI[4][4];
  int wave = tid >> 6, lane = tid & 63;
  if (lane == 0) {
    #pragma unroll
    for (int q = 0; q < 4; ++q) redI[wave][q] = vals[q];
  }
  __syncthreads();
  if (tid == 0) {
    const float invJ = 1.0f / (float)J_DIM;
    ip_solve<N>(i,
      (redI[0][0] + redI[1][0] + redI[2][0] + redI[3][0]) * invJ,
      (redI[0][1] + redI[1][1] + redI[2][1] + redI[3][1]) * invJ,
      (redI[0][2] + redI[1][2] + redI[2][2] + redI[3][2]) * invJ,
      (redI[0][3] + redI[1][3] + redI[2][3] + redI[3][3]) * invJ, W);
  }
}

// ---------------- standalone wrappers ----------------
template<int N>
__global__ __launch_bounds__(256) void k_nmfT(
    const float4* __restrict__ Xq, float* __restrict__ T,
    const float* __restrict__ V, const float* __restrict__ W,
    float* __restrict__ YdR)
{
  nmfT_body<N>(blockIdx.x, threadIdx.x, Xq, T, V, W, YdR);
}

template<int N>
__global__ __launch_bounds__(256) void k_ip(
    const float4* __restrict__ Xq, const float* __restrict__ T,
    const float* __restrict__ V, float* __restrict__ W)
{
  ip_body<N>(blockIdx.x, threadIdx.x, Xq, T, V, W);
}

// fused two-population with XCD-pairing swizzle:
// group of 16 blocks: slots 0-7 = ip for freqs g*8+0..7, slots 8-15 = nmfT for
// the same freqs. Blocks p and p+8 share b%8 => same XCD under round-robin =>
// the nmfT read of row i hits the XCD L2 lines fetched by ip.
template<int N_IP, int N_T>
__global__ __launch_bounds__(256) void k_fused(
    const float4* __restrict__ Xq, float* __restrict__ T,
    const float* __restrict__ V, float* __restrict__ W,
    float* __restrict__ YdR)
{
  int b = blockIdx.x;
  int p, pop;
  if (b >= 2048) { p = 1024; pop = b - 2048; }
  else { pop = (b >> 3) & 1; p = ((b >> 4) << 3) | (b & 7); }
  if (pop == 0)
    ip_body<N_IP>(p, threadIdx.x, Xq, T, V, W);
  else
    nmfT_body<N_T>(p, threadIdx.x, Xq, T, V, W, YdR);
}

// ---------------- NMF V-step: partials + last-block finalize -----------------
// grid: 256 blocks = 8 j-groups x 32 i-chunks (33 i's each).
template<int N>
__global__ __launch_bounds__(256) void k_part(
    float* __restrict__ T, float* __restrict__ V,
    const float* __restrict__ YdR,
    float* __restrict__ Pn, float* __restrict__ Pd,
    unsigned int* __restrict__ ctr)
{
  const int tid = threadIdx.x;
  const int jb = blockIdx.x & 7;
  const int c  = blockIdx.x >> 3;          // 0..31
  const int j  = jb * 256 + tid;
  const int i0 = c * CHI;
  const int ni = min(CHI, I_DIM - i0);
  __shared__ float sT[CHI * K_B];
  for (int s = tid; s < ni * K_B; s += 256) sT[s] = T[(N * I_DIM + i0) * K_B + s];
  __syncthreads();
  float v[K_B];
  #pragma unroll
  for (int k = 0; k < K_B; ++k) v[k] = V[(N * K_B + k) * J_DIM + j];
  float num[K_B], den[K_B];
  #pragma unroll
  for (int k = 0; k < K_B; ++k) { num[k] = 0.f; den[k] = 0.f; }
  for (int ii = 0; ii < ni; ++ii) {
    float ydr = YdR[(size_t)(i0 + ii) * J_DIM + j];
    float rn = 0.f;
    #pragma unroll
    for (int k = 0; k < K_B; ++k) rn += sT[ii * K_B + k] * v[k];
    float rd2 = 1.0f / (fabsf(rn) + EPSF);
    #pragma unroll
    for (int k = 0; k < K_B; ++k) {
      num[k] += sT[ii * K_B + k] * ydr;
      den[k] += sT[ii * K_B + k] * rd2;
    }
  }
  #pragma unroll
  for (int k = 0; k < K_B; ++k) {
    Pn[((size_t)c * K_B + k) * J_DIM + j] = num[k];
    Pd[((size_t)c * K_B + k) * J_DIM + j] = den[k];
  }
  __threadfence();          // release: make this thread's partials visible
  __syncthreads();          // all threads of block past their fences
  __shared__ int lastFlag;
  if (tid == 0) {
    unsigned int old = atomicAdd(&ctr[jb], 1u);
    lastFlag = ((old & 31u) == 31u) ? 1 : 0;   // 32 blocks per jb per dispatch
  }
  __syncthreads();
  if (lastFlag) {
    __threadfence();        // acquire: see all other blocks' partials
    #pragma unroll
    for (int k = 0; k < K_B; ++k) {
      float nm = 0.f, dn = 0.f;
      for (int c2 = 0; c2 < NCH; ++c2) {
        nm += Pn[((size_t)c2 * K_B + k) * J_DIM + j];
        dn += Pd[((size_t)c2 * K_B + k) * J_DIM + j];
      }
      V[(N * K_B + k) * J_DIM + j] *= sqrtf(nm / (dn + EPSF));
    }
  }
}

// ---------------- output: Y = W @ Xc, layout (N, J, I, 2) --------------------
__global__ __launch_bounds__(256) void k_out(
    const float* __restrict__ X, const float* __restrict__ W, float* __restrict__ out)
{
  const int j = blockIdx.x;
  const int i = blockIdx.y * 256 + threadIdx.x;
  if (i >= I_DIM) return;
  const float2* __restrict__ X2 = (const float2*)X;
  float2 x0 = X2[(size_t)(0 * J_DIM + j) * I_DIM + i];
  float2 x1 = X2[(size_t)(1 * J_DIM + j) * I_DIM + i];
  const float4* __restrict__ W4 = (const float4*)W;
  float4 w0 = W4[i * 2 + 0];
  float4 w1 = W4[i * 2 + 1];
  float2* __restrict__ O = (float2*)out;
  float yr = w0.x * x0.x - w0.y * x0.y + w0.z * x1.x - w0.w * x1.y;
  float yi = w0.x * x0.y + w0.y * x0.x + w0.z * x1.y + w0.w * x1.x;
  O[(size_t)(0 * J_DIM + j) * I_DIM + i] = make_float2(yr, yi);
  yr = w1.x * x0.x - w1.y * x0.y + w1.z * x1.x - w1.w * x1.y;
  yi = w1.x * x0.y + w1.y * x0.x + w1.z * x1.y + w1.w * x1.x;
  O[(size_t)(1 * J_DIM + j) * I_DIM + i] = make_float2(yr, yi);
}

// ---------------- launch ----------------
extern "C" void kernel_launch(void* const* d_in, const int* in_sizes, int n_in,
                              void* d_out, int out_size, void* d_ws, size_t ws_size,
                              hipStream_t stream) {
  const float* X  = (const float*)d_in[0];   // (2, 2048, 1025, 2)
  const float* T0 = (const float*)d_in[1];   // (1025, 8, 2)
  const float* V0 = (const float*)d_in[2];   // (8, 2048, 2)
  float* ws = (float*)d_ws;
  // workspace layout (floats)
  float4* Xq = (float4*)ws;           // 1025*2048 float4 = 8396800 floats
  float* YdR = ws + 8396800;          // 2099200
  float* T   = ws + 10496000;         // 16400
  float* V   = ws + 10512400;         // 32768 (scalar [n][k][j])
  float* W   = ws + 10545168;         // 8200 (16B aligned)
  float* Pn  = ws + 10553368;         // 32*8*2048 = 524288
  float* Pd  = ws + 11077656;         // 524288
  unsigned int* ctr = (unsigned int*)(ws + 11601944);  // 8
  float* out = (float*)d_out;

  k_tr_init<<<dim3(33, 64), dim3(32, 8), 0, stream>>>(X, Xq, T0, V0, T, V, W, ctr);
  k_nmfT<0><<<I_DIM, 256, 0, stream>>>(Xq, T, V, W, YdR);
  for (int it = 0; it < 5; ++it) {
    k_part<0><<<8 * NCH, 256, 0, stream>>>(T, V, YdR, Pn, Pd, ctr);
    k_fused<0, 1><<<2 * I_DIM, 256, 0, stream>>>(Xq, T, V, W, YdR);
    k_part<1><<<8 * NCH, 256, 0, stream>>>(T, V, YdR, Pn, Pd, ctr);
    if (it < 4) {
      k_fused<1, 0><<<2 * I_DIM, 256, 0, stream>>>(Xq, T, V, W, YdR);
    } else {
      k_ip<1><<<I_DIM, 256, 0, stream>>>(Xq, T, V, W);
    }
  }
  k_out<<<dim3(J_DIM, 5), 256, 0, stream>>>(X, W, out);
}

// Round 6
// 355.030 us; speedup vs baseline: 3.7415x; 3.7415x over previous
//
#include <hip/hip_runtime.h>

#define I_DIM 1025
#define J_DIM 2048
#define K_B 8
#define IC 33            // i-chunks of 32 (last chunk has 1)
#define EPSF 1e-20f

// ---------------- helpers ----------------

template<int NV>
__device__ __forceinline__ void shflReduce(float* v) {
  #pragma unroll
  for (int off = 32; off > 0; off >>= 1) {
    #pragma unroll
    for (int q = 0; q < NV; ++q) v[q] += __shfl_down(v[q], off);
  }
}

__device__ __forceinline__ float2 cmul(float2 a, float2 b) {
  return make_float2(a.x*b.x - a.y*b.y, a.x*b.y + a.y*b.x);
}
__device__ __forceinline__ float2 cadd(float2 a, float2 b) {
  return make_float2(a.x + b.x, a.y + b.y);
}
__device__ __forceinline__ float2 csub(float2 a, float2 b) {
  return make_float2(a.x - b.x, a.y - b.y);
}
__device__ __forceinline__ float2 cdiv(float2 a, float2 b) {
  float s = 1.0f / (b.x*b.x + b.y*b.y);
  return make_float2((a.x*b.x + a.y*b.y)*s, (a.y*b.x - a.x*b.y)*s);
}

// ---------------- transpose X -> Xq[i][j]=(re0,im0,re1,im1), + init T/V/W ----
// T layout: [n][i][k]; V layout: [n][k][j] scalar; W: [i][n][m][c]
__global__ __launch_bounds__(256) void k_tr_init(
    const float* __restrict__ X, float4* __restrict__ Xq,
    const float* __restrict__ T0, const float* __restrict__ V0,
    float* __restrict__ T, float* __restrict__ V, float* __restrict__ W)
{
  const int tx = threadIdx.x, ty = threadIdx.y;  // (32, 8)
  const int lt = ty * 32 + tx;
  const int bid = blockIdx.y * 33 + blockIdx.x;
  int t = bid * 256 + lt;
  if (t < 2 * K_B * J_DIM) {               // V: 32768
    int n = t / (K_B * J_DIM);
    int r = t % (K_B * J_DIM);
    int k = r / J_DIM, j = r % J_DIM;
    V[t] = V0[(k * J_DIM + j) * 2 + n];
  }
  if (t < 2 * I_DIM * K_B) {               // T: 16400
    int n = t / (I_DIM * K_B);
    int r = t % (I_DIM * K_B);
    int i = r / K_B, k = r % K_B;
    T[t] = T0[(i * K_B + k) * 2 + n];
  }
  if (t < I_DIM * 8) {                     // W: 8200
    int u = t & 7;
    int c = u & 1, m = (u >> 1) & 1, n = u >> 2;
    W[t] = (n == m && c == 0) ? 1.0f : 0.0f;
  }
  // ---- transpose ----
  __shared__ float t0r[32][33], t0i[32][33], t1r[32][33], t1i[32][33];
  const int i0 = blockIdx.x * 32, j0 = blockIdx.y * 32;
  const float2* __restrict__ X2 = (const float2*)X;
  #pragma unroll
  for (int jj = 0; jj < 4; ++jj) {
    int jl = ty + jj * 8;
    int i = i0 + tx;
    if (i < I_DIM) {
      float2 v0 = X2[(size_t)(0 * J_DIM + j0 + jl) * I_DIM + i];
      float2 v1 = X2[(size_t)(1 * J_DIM + j0 + jl) * I_DIM + i];
      t0r[jl][tx] = v0.x; t0i[jl][tx] = v0.y;
      t1r[jl][tx] = v1.x; t1i[jl][tx] = v1.y;
    }
  }
  __syncthreads();
  #pragma unroll
  for (int ii = 0; ii < 4; ++ii) {
    int il = ty + ii * 8;
    int i = i0 + il;
    if (i < I_DIM) {
      Xq[(size_t)i * J_DIM + j0 + tx] =
        make_float4(t0r[tx][il], t0i[tx][il], t1r[tx][il], t1i[tx][il]);
    }
  }
}

// ---------------- NMF T-step body: upfront X loads, lane-contiguous ----------
template<int N>
__device__ __forceinline__ void nmfT_body(
    int i, int tid,
    const float4* __restrict__ Xq,
    float* __restrict__ T, const float* __restrict__ V,
    const float* __restrict__ W, float* __restrict__ YdR)
{
  float4 xs[8];
  #pragma unroll
  for (int u = 0; u < 8; ++u) xs[u] = Xq[(size_t)i * J_DIM + u * 256 + tid];

  const float4 w = ((const float4*)W)[i * 2 + N];
  float t[K_B];
  const int trow = (N * I_DIM + i) * K_B;
  #pragma unroll
  for (int k = 0; k < K_B; ++k) t[k] = T[trow + k];

  float num[K_B], den[K_B];
  #pragma unroll
  for (int k = 0; k < K_B; ++k) { num[k] = 0.f; den[k] = 0.f; }

  #pragma unroll
  for (int u = 0; u < 8; ++u) {
    int j = u * 256 + tid;
    float v[K_B];
    float rn = 0.f;
    #pragma unroll
    for (int k = 0; k < K_B; ++k) {
      v[k] = V[(N * K_B + k) * J_DIM + j];
      rn += t[k] * v[k];
    }
    float4 x = xs[u];
    float yr = w.x * x.x - w.y * x.y + w.z * x.z - w.w * x.w;
    float yi = w.x * x.y + w.y * x.x + w.z * x.w + w.w * x.z;
    float rd = 1.0f / (fabsf(rn) + EPSF);
    float ydr = (yr * yr + yi * yi) * rd * rd;
    YdR[(size_t)i * J_DIM + j] = ydr;
    #pragma unroll
    for (int k = 0; k < K_B; ++k) { num[k] += ydr * v[k]; den[k] += rd * v[k]; }
  }

  float vals[16];
  #pragma unroll
  for (int k = 0; k < K_B; ++k) { vals[k] = num[k]; vals[K_B + k] = den[k]; }
  shflReduce<16>(vals);
  __shared__ float redT[4][16];
  int wave = tid >> 6, lane = tid & 63;
  if (lane == 0) {
    #pragma unroll
    for (int q = 0; q < 16; ++q) redT[wave][q] = vals[q];
  }
  __syncthreads();
  if (tid < K_B) {
    float nm = redT[0][tid] + redT[1][tid] + redT[2][tid] + redT[3][tid];
    float dn = redT[0][tid + 8] + redT[1][tid + 8] + redT[2][tid + 8] + redT[3][tid + 8];
    T[trow + tid] *= sqrtf(nm / (dn + EPSF));
  }
}

// ---------------- 2x2 solve epilogue (one thread) ----------------------------
template<int N>
__device__ __forceinline__ void ip_solve(
    int i, float D00, float p, float q, float D11, float* __restrict__ W)
{
  D00 += EPSF; D11 += EPSF;
  float2 D01 = make_float2(p, q);
  float2 D10 = make_float2(p, -q);
  float4 w0 = ((const float4*)W)[i * 2 + 0];
  float4 w1 = ((const float4*)W)[i * 2 + 1];
  float2 W00 = make_float2(w0.x, w0.y), W01 = make_float2(w0.z, w0.w);
  float2 W10 = make_float2(w1.x, w1.y), W11 = make_float2(w1.z, w1.w);
  float2 A00 = cadd(make_float2(W00.x * D00, W00.y * D00), cmul(W01, D10));
  float2 A01 = cadd(cmul(W00, D01), make_float2(W01.x * D11, W01.y * D11));
  float2 A10 = cadd(make_float2(W10.x * D00, W10.y * D00), cmul(W11, D10));
  float2 A11 = cadd(cmul(W10, D01), make_float2(W11.x * D11, W11.y * D11));
  float2 det = csub(cmul(A00, A11), cmul(A01, A10));
  float2 b0, b1;
  if (N == 0) {
    b0 = cdiv(A11, det);
    b1 = cdiv(make_float2(-A10.x, -A10.y), det);
  } else {
    b0 = cdiv(make_float2(-A01.x, -A01.y), det);
    b1 = cdiv(A00, det);
  }
  float2 Db0 = cadd(make_float2(D00 * b0.x, D00 * b0.y), cmul(D01, b1));
  float2 Db1 = cadd(cmul(D10, b0), make_float2(D11 * b1.x, D11 * b1.y));
  float ip = b0.x * Db0.x + b0.y * Db0.y + b1.x * Db1.x + b1.y * Db1.y;
  float inv = 1.0f / sqrtf(ip + EPSF);
  ((float4*)W)[i * 2 + N] = make_float4(b0.x * inv, -b0.y * inv, b1.x * inv, -b1.y * inv);
}

// ---------------- IP body: upfront X loads, lane-contiguous ------------------
template<int N>
__device__ __forceinline__ void ip_body(
    int i, int tid,
    const float4* __restrict__ Xq,
    const float* __restrict__ T, const float* __restrict__ V,
    float* __restrict__ W)
{
  float4 xs[8];
  #pragma unroll
  for (int u = 0; u < 8; ++u) xs[u] = Xq[(size_t)i * J_DIM + u * 256 + tid];

  float t[K_B];
  const int trow = (N * I_DIM + i) * K_B;
  #pragma unroll
  for (int k = 0; k < K_B; ++k) t[k] = T[trow + k];

  float d00 = 0.f, d01r = 0.f, d01i = 0.f, d11 = 0.f;
  #pragma unroll
  for (int u = 0; u < 8; ++u) {
    int j = u * 256 + tid;
    float rn = 0.f;
    #pragma unroll
    for (int k = 0; k < K_B; ++k) rn += t[k] * V[(N * K_B + k) * J_DIM + j];
    float wgt = 1.0f / (rn + EPSF);   // reference: 1/(Rn + IP_EPS), no abs
    float4 x = xs[u];
    d00 += (x.x * x.x + x.y * x.y) * wgt;
    d11 += (x.z * x.z + x.w * x.w) * wgt;
    d01r += (x.x * x.z + x.y * x.w) * wgt;
    d01i += (x.y * x.z - x.x * x.w) * wgt;
  }
  float vals[4] = {d00, d01r, d01i, d11};
  shflReduce<4>(vals);
  __shared__ float redI[4][4];
  int wave = tid >> 6, lane = tid & 63;
  if (lane == 0) {
    #pragma unroll
    for (int q = 0; q < 4; ++q) redI[wave][q] = vals[q];
  }
  __syncthreads();
  if (tid == 0) {
    const float invJ = 1.0f / (float)J_DIM;
    ip_solve<N>(i,
      (redI[0][0] + redI[1][0] + redI[2][0] + redI[3][0]) * invJ,
      (redI[0][1] + redI[1][1] + redI[2][1] + redI[3][1]) * invJ,
      (redI[0][2] + redI[1][2] + redI[2][2] + redI[3][2]) * invJ,
      (redI[0][3] + redI[1][3] + redI[2][3] + redI[3][3]) * invJ, W);
  }
}

// ---------------- standalone wrappers ----------------
template<int N>
__global__ __launch_bounds__(256) void k_nmfT(
    const float4* __restrict__ Xq, float* __restrict__ T,
    const float* __restrict__ V, const float* __restrict__ W,
    float* __restrict__ YdR)
{
  nmfT_body<N>(blockIdx.x, threadIdx.x, Xq, T, V, W, YdR);
}

template<int N>
__global__ __launch_bounds__(256) void k_ip(
    const float4* __restrict__ Xq, const float* __restrict__ T,
    const float* __restrict__ V, float* __restrict__ W)
{
  ip_body<N>(blockIdx.x, threadIdx.x, Xq, T, V, W);
}

// fused two-population with XCD-pairing swizzle: in each 16-block group,
// slots 0-7 = ip for freqs g*8+0..7, slots 8-15 = nmfT for the same freqs.
// Blocks p and p+8 share b%8 => same XCD => shared L2 lines for row i.
template<int N_IP, int N_T>
__global__ __launch_bounds__(256) void k_fused(
    const float4* __restrict__ Xq, float* __restrict__ T,
    const float* __restrict__ V, float* __restrict__ W,
    float* __restrict__ YdR)
{
  int b = blockIdx.x;
  int p, pop;
  if (b >= 2048) { p = 1024; pop = b - 2048; }
  else { pop = (b >> 3) & 1; p = ((b >> 4) << 3) | (b & 7); }
  if (pop == 0)
    ip_body<N_IP>(p, threadIdx.x, Xq, T, V, W);
  else
    nmfT_body<N_T>(p, threadIdx.x, Xq, T, V, W, YdR);
}

// ---------------- NMF V-step, phase A: partial sums (no fences!) -------------
// grid: 8 j-groups x 33 i-chunks = 264 blocks; thread owns one j column
template<int N>
__global__ __launch_bounds__(256) void k_part(
    const float* __restrict__ T, const float* __restrict__ V,
    const float* __restrict__ YdR,
    float* __restrict__ Pn, float* __restrict__ Pd)
{
  const int tid = threadIdx.x;
  const int jb = blockIdx.x & 7;
  const int c  = blockIdx.x >> 3;          // 0..32
  const int j  = jb * 256 + tid;
  const int i0 = c * 32;
  const int ni = min(32, I_DIM - i0);
  __shared__ float sT[32 * K_B];
  if (tid < ni * K_B) sT[tid] = T[(N * I_DIM + i0) * K_B + tid];
  __syncthreads();
  float v[K_B];
  #pragma unroll
  for (int k = 0; k < K_B; ++k) v[k] = V[(N * K_B + k) * J_DIM + j];
  float num[K_B], den[K_B];
  #pragma unroll
  for (int k = 0; k < K_B; ++k) { num[k] = 0.f; den[k] = 0.f; }

  if (ni == 32) {
    // fast path: prefetch YdR in groups of 8 to keep 8 loads in flight
    #pragma unroll
    for (int g = 0; g < 4; ++g) {
      float yd[8];
      #pragma unroll
      for (int q = 0; q < 8; ++q)
        yd[q] = YdR[(size_t)(i0 + g * 8 + q) * J_DIM + j];
      #pragma unroll
      for (int q = 0; q < 8; ++q) {
        const int ii = g * 8 + q;
        float rn = 0.f;
        #pragma unroll
        for (int k = 0; k < K_B; ++k) rn += sT[ii * K_B + k] * v[k];
        float rd2 = 1.0f / (fabsf(rn) + EPSF);
        #pragma unroll
        for (int k = 0; k < K_B; ++k) {
          num[k] += sT[ii * K_B + k] * yd[q];
          den[k] += sT[ii * K_B + k] * rd2;
        }
      }
    }
  } else {
    for (int ii = 0; ii < ni; ++ii) {
      float ydr = YdR[(size_t)(i0 + ii) * J_DIM + j];
      float rn = 0.f;
      #pragma unroll
      for (int k = 0; k < K_B; ++k) rn += sT[ii * K_B + k] * v[k];
      float rd2 = 1.0f / (fabsf(rn) + EPSF);
      #pragma unroll
      for (int k = 0; k < K_B; ++k) {
        num[k] += sT[ii * K_B + k] * ydr;
        den[k] += sT[ii * K_B + k] * rd2;
      }
    }
  }
  #pragma unroll
  for (int k = 0; k < K_B; ++k) {
    Pn[((size_t)c * K_B + k) * J_DIM + j] = num[k];
    Pd[((size_t)c * K_B + k) * J_DIM + j] = den[k];
  }
}

// ---------------- NMF V-step, phase B: finalize ------------------------------
template<int N>
__global__ __launch_bounds__(256) void k_fin(
    float* __restrict__ V, const float* __restrict__ Pn,
    const float* __restrict__ Pd)
{
  const int t = blockIdx.x * 256 + threadIdx.x;   // k*2048+j, 16384 total
  float nm = 0.f, dn = 0.f;
  #pragma unroll
  for (int c = 0; c < IC; ++c) {
    nm += Pn[(size_t)c * (K_B * J_DIM) + t];
    dn += Pd[(size_t)c * (K_B * J_DIM) + t];
  }
  V[N * (K_B * J_DIM) + t] *= sqrtf(nm / (dn + EPSF));
}

// ---------------- output: Y = W @ Xc, layout (N, J, I, 2) --------------------
__global__ __launch_bounds__(256) void k_out(
    const float* __restrict__ X, const float* __restrict__ W, float* __restrict__ out)
{
  const int j = blockIdx.x;
  const int i = blockIdx.y * 256 + threadIdx.x;
  if (i >= I_DIM) return;
  const float2* __restrict__ X2 = (const float2*)X;
  float2 x0 = X2[(size_t)(0 * J_DIM + j) * I_DIM + i];
  float2 x1 = X2[(size_t)(1 * J_DIM + j) * I_DIM + i];
  const float4* __restrict__ W4 = (const float4*)W;
  float4 w0 = W4[i * 2 + 0];
  float4 w1 = W4[i * 2 + 1];
  float2* __restrict__ O = (float2*)out;
  float yr = w0.x * x0.x - w0.y * x0.y + w0.z * x1.x - w0.w * x1.y;
  float yi = w0.x * x0.y + w0.y * x0.x + w0.z * x1.y + w0.w * x1.x;
  O[(size_t)(0 * J_DIM + j) * I_DIM + i] = make_float2(yr, yi);
  yr = w1.x * x0.x - w1.y * x0.y + w1.z * x1.x - w1.w * x1.y;
  yi = w1.x * x0.y + w1.y * x0.x + w1.z * x1.y + w1.w * x1.x;
  O[(size_t)(1 * J_DIM + j) * I_DIM + i] = make_float2(yr, yi);
}

// ---------------- launch ----------------
extern "C" void kernel_launch(void* const* d_in, const int* in_sizes, int n_in,
                              void* d_out, int out_size, void* d_ws, size_t ws_size,
                              hipStream_t stream) {
  const float* X  = (const float*)d_in[0];   // (2, 2048, 1025, 2)
  const float* T0 = (const float*)d_in[1];   // (1025, 8, 2)
  const float* V0 = (const float*)d_in[2];   // (8, 2048, 2)
  float* ws = (float*)d_ws;
  // workspace layout (floats)
  float4* Xq = (float4*)ws;           // 1025*2048 float4 = 8396800 floats
  float* YdR = ws + 8396800;          // 2099200
  float* T   = ws + 10496000;         // 16400
  float* V   = ws + 10512400;         // 32768 (scalar [n][k][j])
  float* W   = ws + 10545168;         // 8200 (16B aligned)
  float* Pn  = ws + 10553368;         // 33*8*2048 = 540672
  float* Pd  = ws + 11094040;         // 540672
  float* out = (float*)d_out;

  k_tr_init<<<dim3(33, 64), dim3(32, 8), 0, stream>>>(X, Xq, T0, V0, T, V, W);
  k_nmfT<0><<<I_DIM, 256, 0, stream>>>(Xq, T, V, W, YdR);
  for (int it = 0; it < 5; ++it) {
    k_part<0><<<8 * IC, 256, 0, stream>>>(T, V, YdR, Pn, Pd);
    k_fin<0><<<64, 256, 0, stream>>>(V, Pn, Pd);
    k_fused<0, 1><<<2 * I_DIM, 256, 0, stream>>>(Xq, T, V, W, YdR);
    k_part<1><<<8 * IC, 256, 0, stream>>>(T, V, YdR, Pn, Pd);
    k_fin<1><<<64, 256, 0, stream>>>(V, Pn, Pd);
    if (it < 4) {
      k_fused<1, 0><<<2 * I_DIM, 256, 0, stream>>>(Xq, T, V, W, YdR);
    } else {
      k_ip<1><<<I_DIM, 256, 0, stream>>>(Xq, T, V, W);
    }
  }
  k_out<<<dim3(J_DIM, 5), 256, 0, stream>>>(X, W, out);
}

// Round 7
// 313.398 us; speedup vs baseline: 4.2385x; 1.1328x over previous
//
#include <hip/hip_runtime.h>

#define I_DIM 1025
#define J_DIM 2048
#define K_B 8
#define IC 33            // i-chunks of 32 (last has 1)
#define EPSF 1e-20f

// ---------------- helpers ----------------

__device__ __forceinline__ int rev4i(int x) {
  return ((x & 1) << 3) | ((x & 2) << 1) | ((x & 4) >> 1) | ((x & 8) >> 3);
}

// value-halving butterfly: 16 vals over 64 lanes in 17 shuffles.
// Post: vals[0] of lane l (l<16) holds total of value rev4i(l).
__device__ __forceinline__ void foldReduce16(float* vals, int lane) {
  #pragma unroll
  for (int step = 0; step < 4; ++step) {
    const int nv = 8 >> step;           // 8,4,2,1
    const int bit = (lane >> step) & 1;
    #pragma unroll
    for (int q = 0; q < nv; ++q) {
      float a = vals[q], b = vals[q + nv];
      float send = bit ? a : b;
      float keep = bit ? b : a;
      vals[q] = keep + __shfl_xor(send, 1 << step);
    }
  }
  vals[0] += __shfl_xor(vals[0], 16);
  vals[0] += __shfl_xor(vals[0], 32);
}

// 4 vals over 64 lanes. Post: lane l (l<4) holds value rev2(l): 0,2,1,3.
__device__ __forceinline__ void foldReduce4(float* vals, int lane) {
  #pragma unroll
  for (int step = 0; step < 2; ++step) {
    const int nv = 2 >> step;           // 2,1
    const int bit = (lane >> step) & 1;
    #pragma unroll
    for (int q = 0; q < nv; ++q) {
      float a = vals[q], b = vals[q + nv];
      float send = bit ? a : b;
      float keep = bit ? b : a;
      vals[q] = keep + __shfl_xor(send, 1 << step);
    }
  }
  vals[0] += __shfl_xor(vals[0], 4);
  vals[0] += __shfl_xor(vals[0], 8);
  vals[0] += __shfl_xor(vals[0], 16);
  vals[0] += __shfl_xor(vals[0], 32);
}

__device__ __forceinline__ float2 cmul(float2 a, float2 b) {
  return make_float2(a.x*b.x - a.y*b.y, a.x*b.y + a.y*b.x);
}
__device__ __forceinline__ float2 cadd(float2 a, float2 b) {
  return make_float2(a.x + b.x, a.y + b.y);
}
__device__ __forceinline__ float2 csub(float2 a, float2 b) {
  return make_float2(a.x - b.x, a.y - b.y);
}
__device__ __forceinline__ float2 cdiv(float2 a, float2 b) {
  float s = 1.0f / (b.x*b.x + b.y*b.y);
  return make_float2((a.x*b.x + a.y*b.y)*s, (a.y*b.x - a.x*b.y)*s);
}

// ---------------- transpose X -> Xq[i][j]=(re0,im0,re1,im1), + init T/V/W ----
// T: [n][i][k]; V: [n][j][k] (float4-pair per j); W: [i][n][m][c]
__global__ __launch_bounds__(256) void k_tr_init(
    const float* __restrict__ X, float4* __restrict__ Xq,
    const float* __restrict__ T0, const float* __restrict__ V0,
    float* __restrict__ T, float* __restrict__ V, float* __restrict__ W)
{
  const int tx = threadIdx.x, ty = threadIdx.y;  // (32, 8)
  const int lt = ty * 32 + tx;
  const int bid = blockIdx.y * 33 + blockIdx.x;
  int t = bid * 256 + lt;
  if (t < 2 * K_B * J_DIM) {               // V: 32768, [n][j][k]
    int n = t >> 14;
    int r = t & 16383;
    int j = r >> 3, k = r & 7;
    V[t] = V0[(k * J_DIM + j) * 2 + n];
  }
  if (t < 2 * I_DIM * K_B) {               // T: 16400
    int n = t / (I_DIM * K_B);
    int r = t % (I_DIM * K_B);
    int i = r / K_B, k = r % K_B;
    T[t] = T0[(i * K_B + k) * 2 + n];
  }
  if (t < I_DIM * 8) {                     // W: 8200
    int u = t & 7;
    int c = u & 1, m = (u >> 1) & 1, n = u >> 2;
    W[t] = (n == m && c == 0) ? 1.0f : 0.0f;
  }
  // ---- transpose ----
  __shared__ float t0r[32][33], t0i[32][33], t1r[32][33], t1i[32][33];
  const int i0 = blockIdx.x * 32, j0 = blockIdx.y * 32;
  const float2* __restrict__ X2 = (const float2*)X;
  #pragma unroll
  for (int jj = 0; jj < 4; ++jj) {
    int jl = ty + jj * 8;
    int i = i0 + tx;
    if (i < I_DIM) {
      float2 v0 = X2[(size_t)(0 * J_DIM + j0 + jl) * I_DIM + i];
      float2 v1 = X2[(size_t)(1 * J_DIM + j0 + jl) * I_DIM + i];
      t0r[jl][tx] = v0.x; t0i[jl][tx] = v0.y;
      t1r[jl][tx] = v1.x; t1i[jl][tx] = v1.y;
    }
  }
  __syncthreads();
  #pragma unroll
  for (int ii = 0; ii < 4; ++ii) {
    int il = ty + ii * 8;
    int i = i0 + il;
    if (i < I_DIM) {
      Xq[(size_t)i * J_DIM + j0 + tx] =
        make_float4(t0r[tx][il], t0i[tx][il], t1r[tx][il], t1i[tx][il]);
    }
  }
}

// ---------------- NMF T-step body --------------------------------------------
template<int N>
__device__ __forceinline__ void nmfT_body(
    int i, int tid,
    const float4* __restrict__ Xq,
    float* __restrict__ T, const float* __restrict__ V,
    const float* __restrict__ W, float* __restrict__ YdR)
{
  float4 xs[8];
  #pragma unroll
  for (int u = 0; u < 8; ++u) xs[u] = Xq[(size_t)i * J_DIM + u * 256 + tid];

  const float4 w = ((const float4*)W)[i * 2 + N];
  float t[K_B];
  const int trow = (N * I_DIM + i) * K_B;
  #pragma unroll
  for (int k = 0; k < K_B; ++k) t[k] = T[trow + k];

  float num[K_B], den[K_B];
  #pragma unroll
  for (int k = 0; k < K_B; ++k) { num[k] = 0.f; den[k] = 0.f; }

  const float4* __restrict__ V4 = (const float4*)V;
  #pragma unroll
  for (int u = 0; u < 8; ++u) {
    int j = u * 256 + tid;
    float4 va = V4[(N * J_DIM + j) * 2 + 0];
    float4 vb = V4[(N * J_DIM + j) * 2 + 1];
    float v[K_B] = {va.x, va.y, va.z, va.w, vb.x, vb.y, vb.z, vb.w};
    float rn = 0.f;
    #pragma unroll
    for (int k = 0; k < K_B; ++k) rn += t[k] * v[k];
    float4 x = xs[u];
    float yr = w.x * x.x - w.y * x.y + w.z * x.z - w.w * x.w;
    float yi = w.x * x.y + w.y * x.x + w.z * x.w + w.w * x.z;
    float rd = 1.0f / (fabsf(rn) + EPSF);
    float ydr = (yr * yr + yi * yi) * rd * rd;
    YdR[(size_t)i * J_DIM + j] = ydr;
    #pragma unroll
    for (int k = 0; k < K_B; ++k) { num[k] += ydr * v[k]; den[k] += rd * v[k]; }
  }

  float vals[16];
  #pragma unroll
  for (int k = 0; k < K_B; ++k) { vals[k] = num[k]; vals[K_B + k] = den[k]; }
  const int wave = tid >> 6, lane = tid & 63;
  foldReduce16(vals, lane);
  __shared__ float redT[4][16];
  if (lane < 16) redT[wave][lane] = vals[0];   // slot l holds value rev4i(l)
  __syncthreads();
  if (tid < K_B) {
    int r = rev4i(tid);                        // value tid at slot r; tid+8 at r+1
    float nm = redT[0][r] + redT[1][r] + redT[2][r] + redT[3][r];
    float dn = redT[0][r+1] + redT[1][r+1] + redT[2][r+1] + redT[3][r+1];
    T[trow + tid] *= sqrtf(nm / (dn + EPSF));
  }
}

// ---------------- 2x2 solve epilogue (one thread) ----------------------------
template<int N>
__device__ __forceinline__ void ip_solve(
    int i, float D00, float p, float q, float D11, float* __restrict__ W)
{
  D00 += EPSF; D11 += EPSF;
  float2 D01 = make_float2(p, q);
  float2 D10 = make_float2(p, -q);
  float4 w0 = ((const float4*)W)[i * 2 + 0];
  float4 w1 = ((const float4*)W)[i * 2 + 1];
  float2 W00 = make_float2(w0.x, w0.y), W01 = make_float2(w0.z, w0.w);
  float2 W10 = make_float2(w1.x, w1.y), W11 = make_float2(w1.z, w1.w);
  float2 A00 = cadd(make_float2(W00.x * D00, W00.y * D00), cmul(W01, D10));
  float2 A01 = cadd(cmul(W00, D01), make_float2(W01.x * D11, W01.y * D11));
  float2 A10 = cadd(make_float2(W10.x * D00, W10.y * D00), cmul(W11, D10));
  float2 A11 = cadd(cmul(W10, D01), make_float2(W11.x * D11, W11.y * D11));
  float2 det = csub(cmul(A00, A11), cmul(A01, A10));
  float2 b0, b1;
  if (N == 0) {
    b0 = cdiv(A11, det);
    b1 = cdiv(make_float2(-A10.x, -A10.y), det);
  } else {
    b0 = cdiv(make_float2(-A01.x, -A01.y), det);
    b1 = cdiv(A00, det);
  }
  float2 Db0 = cadd(make_float2(D00 * b0.x, D00 * b0.y), cmul(D01, b1));
  float2 Db1 = cadd(cmul(D10, b0), make_float2(D11 * b1.x, D11 * b1.y));
  float ip = b0.x * Db0.x + b0.y * Db0.y + b1.x * Db1.x + b1.y * Db1.y;
  float inv = 1.0f / sqrtf(ip + EPSF);
  ((float4*)W)[i * 2 + N] = make_float4(b0.x * inv, -b0.y * inv, b1.x * inv, -b1.y * inv);
}

// ---------------- IP body ----------------------------------------------------
template<int N>
__device__ __forceinline__ void ip_body(
    int i, int tid,
    const float4* __restrict__ Xq,
    const float* __restrict__ T, const float* __restrict__ V,
    float* __restrict__ W)
{
  float4 xs[8];
  #pragma unroll
  for (int u = 0; u < 8; ++u) xs[u] = Xq[(size_t)i * J_DIM + u * 256 + tid];

  float t[K_B];
  const int trow = (N * I_DIM + i) * K_B;
  #pragma unroll
  for (int k = 0; k < K_B; ++k) t[k] = T[trow + k];

  const float4* __restrict__ V4 = (const float4*)V;
  float d00 = 0.f, d01r = 0.f, d01i = 0.f, d11 = 0.f;
  #pragma unroll
  for (int u = 0; u < 8; ++u) {
    int j = u * 256 + tid;
    float4 va = V4[(N * J_DIM + j) * 2 + 0];
    float4 vb = V4[(N * J_DIM + j) * 2 + 1];
    float rn = t[0]*va.x + t[1]*va.y + t[2]*va.z + t[3]*va.w
             + t[4]*vb.x + t[5]*vb.y + t[6]*vb.z + t[7]*vb.w;
    float wgt = 1.0f / (rn + EPSF);   // reference: 1/(Rn + IP_EPS), no abs
    float4 x = xs[u];
    d00 += (x.x * x.x + x.y * x.y) * wgt;
    d11 += (x.z * x.z + x.w * x.w) * wgt;
    d01r += (x.x * x.z + x.y * x.w) * wgt;
    d01i += (x.y * x.z - x.x * x.w) * wgt;
  }
  float vals[4] = {d00, d01r, d01i, d11};
  const int wave = tid >> 6, lane = tid & 63;
  foldReduce4(vals, lane);
  __shared__ float redI[4][4];
  if (lane < 4) redI[wave][lane] = vals[0];  // slot l holds value rev2(l): 0,2,1,3
  __syncthreads();
  if (tid == 0) {
    const float invJ = 1.0f / (float)J_DIM;
    float D00 = (redI[0][0] + redI[1][0] + redI[2][0] + redI[3][0]) * invJ;
    float pr  = (redI[0][2] + redI[1][2] + redI[2][2] + redI[3][2]) * invJ;
    float qi  = (redI[0][1] + redI[1][1] + redI[2][1] + redI[3][1]) * invJ;
    float D11 = (redI[0][3] + redI[1][3] + redI[2][3] + redI[3][3]) * invJ;
    ip_solve<N>(i, D00, pr, qi, D11, W);
  }
}

// ---------------- V partials body --------------------------------------------
// pb in [0,264): jb = pb&7, chunk c = pb>>3 (32 i's, last chunk 1)
template<int N>
__device__ __forceinline__ void part_body(
    int pb, int tid,
    const float* __restrict__ T, const float* __restrict__ V,
    const float* __restrict__ YdR,
    float* __restrict__ Pn, float* __restrict__ Pd)
{
  const int jb = pb & 7;
  const int c  = pb >> 3;
  const int j  = jb * 256 + tid;
  const int i0 = c * 32;
  const int ni = min(32, I_DIM - i0);
  __shared__ float sT[32 * K_B];
  if (tid < ni * K_B) sT[tid] = T[(N * I_DIM + i0) * K_B + tid];
  __syncthreads();
  const float4* __restrict__ V4 = (const float4*)V;
  float4 va = V4[(N * J_DIM + j) * 2 + 0];
  float4 vb = V4[(N * J_DIM + j) * 2 + 1];
  float v[K_B] = {va.x, va.y, va.z, va.w, vb.x, vb.y, vb.z, vb.w};
  float num[K_B], den[K_B];
  #pragma unroll
  for (int k = 0; k < K_B; ++k) { num[k] = 0.f; den[k] = 0.f; }

  if (ni == 32) {
    #pragma unroll
    for (int g = 0; g < 4; ++g) {
      float yd[8];
      #pragma unroll
      for (int q = 0; q < 8; ++q)
        yd[q] = YdR[(size_t)(i0 + g * 8 + q) * J_DIM + j];
      #pragma unroll
      for (int q = 0; q < 8; ++q) {
        const int ii = g * 8 + q;
        float rn = 0.f;
        #pragma unroll
        for (int k = 0; k < K_B; ++k) rn += sT[ii * K_B + k] * v[k];
        float rd2 = 1.0f / (fabsf(rn) + EPSF);
        #pragma unroll
        for (int k = 0; k < K_B; ++k) {
          num[k] += sT[ii * K_B + k] * yd[q];
          den[k] += sT[ii * K_B + k] * rd2;
        }
      }
    }
  } else {
    for (int ii = 0; ii < ni; ++ii) {
      float ydr = YdR[(size_t)(i0 + ii) * J_DIM + j];
      float rn = 0.f;
      #pragma unroll
      for (int k = 0; k < K_B; ++k) rn += sT[ii * K_B + k] * v[k];
      float rd2 = 1.0f / (fabsf(rn) + EPSF);
      #pragma unroll
      for (int k = 0; k < K_B; ++k) {
        num[k] += sT[ii * K_B + k] * ydr;
        den[k] += sT[ii * K_B + k] * rd2;
      }
    }
  }
  // partials layout [c][j][k]
  ((float4*)Pn)[((size_t)c * J_DIM + j) * 2 + 0] = make_float4(num[0], num[1], num[2], num[3]);
  ((float4*)Pn)[((size_t)c * J_DIM + j) * 2 + 1] = make_float4(num[4], num[5], num[6], num[7]);
  ((float4*)Pd)[((size_t)c * J_DIM + j) * 2 + 0] = make_float4(den[0], den[1], den[2], den[3]);
  ((float4*)Pd)[((size_t)c * J_DIM + j) * 2 + 1] = make_float4(den[4], den[5], den[6], den[7]);
}

// ---------------- V finalize body --------------------------------------------
template<int N>
__device__ __forceinline__ void fin_body(
    int fb, int tid, float* __restrict__ V,
    const float* __restrict__ Pn, const float* __restrict__ Pd)
{
  const int t = fb * 256 + tid;   // (j,k): j = t>>3, k = t&7; 16384 total
  float nm = 0.f, dn = 0.f;
  #pragma unroll
  for (int c = 0; c < IC; ++c) {
    nm += Pn[(size_t)c * (K_B * J_DIM) + t];
    dn += Pd[(size_t)c * (K_B * J_DIM) + t];
  }
  V[N * (K_B * J_DIM) + t] *= sqrtf(nm / (dn + EPSF));
}

// ---------------- pipeline kernels -------------------------------------------
// S2: part(NP) on blocks [0,264) | nmfT(NT) on [264, 264+1025)
template<int NT, int NP>
__global__ __launch_bounds__(256) void k_s2(
    const float4* __restrict__ Xq, float* __restrict__ T,
    const float* __restrict__ V, const float* __restrict__ W,
    float* __restrict__ YdR_t, const float* __restrict__ YdR_p,
    float* __restrict__ Pn, float* __restrict__ Pd)
{
  if (blockIdx.x < 264)
    part_body<NP>(blockIdx.x, threadIdx.x, T, V, YdR_p, Pn, Pd);
  else
    nmfT_body<NT>(blockIdx.x - 264, threadIdx.x, Xq, T, V, W, YdR_t);
}

// S3: fin(NF) on blocks [0,64) | part(NP) on [64, 64+264)
template<int NF, int NP>
__global__ __launch_bounds__(256) void k_s3(
    float* __restrict__ V,
    const float* __restrict__ Pn_f, const float* __restrict__ Pd_f,
    const float* __restrict__ T, const float* __restrict__ YdR_p,
    float* __restrict__ Pn_p, float* __restrict__ Pd_p)
{
  if (blockIdx.x < 64)
    fin_body<NF>(blockIdx.x, threadIdx.x, V, Pn_f, Pd_f);
  else
    part_body<NP>(blockIdx.x - 64, threadIdx.x, T, V, YdR_p, Pn_p, Pd_p);
}

// S4: fin(NF) on blocks [0,64) | ip(NI) on [64, 64+1025)
template<int NI, int NF>
__global__ __launch_bounds__(256) void k_s4(
    const float4* __restrict__ Xq, const float* __restrict__ T,
    float* __restrict__ V, float* __restrict__ W,
    const float* __restrict__ Pn_f, const float* __restrict__ Pd_f)
{
  if (blockIdx.x < 64)
    fin_body<NF>(blockIdx.x, threadIdx.x, V, Pn_f, Pd_f);
  else
    ip_body<NI>(blockIdx.x - 64, threadIdx.x, Xq, T, V, W);
}

// S1: ip(NI) | nmfT(NT), XCD-paired: in each 16-group, slots 0-7 = ip for
// freqs g*8+0..7, slots 8-15 = nmfT same freqs (b%8 preserved => same XCD).
template<int NT, int NI>
__global__ __launch_bounds__(256) void k_s1(
    const float4* __restrict__ Xq, float* __restrict__ T,
    const float* __restrict__ V, float* __restrict__ W,
    float* __restrict__ YdR_t)
{
  int b = blockIdx.x;
  int p, pop;
  if (b >= 2048) { p = 1024; pop = b - 2048; }
  else { pop = (b >> 3) & 1; p = ((b >> 4) << 3) | (b & 7); }
  if (pop == 0)
    ip_body<NI>(p, threadIdx.x, Xq, T, V, W);
  else
    nmfT_body<NT>(p, threadIdx.x, Xq, T, V, W, YdR_t);
}

// ---------------- standalone wrappers ----------------
template<int N>
__global__ __launch_bounds__(256) void k_nmfT(
    const float4* __restrict__ Xq, float* __restrict__ T,
    const float* __restrict__ V, const float* __restrict__ W,
    float* __restrict__ YdR)
{
  nmfT_body<N>(blockIdx.x, threadIdx.x, Xq, T, V, W, YdR);
}

template<int N>
__global__ __launch_bounds__(256) void k_ip(
    const float4* __restrict__ Xq, const float* __restrict__ T,
    const float* __restrict__ V, float* __restrict__ W)
{
  ip_body<N>(blockIdx.x, threadIdx.x, Xq, T, V, W);
}

// ---------------- output: Y = W @ Xc, layout (N, J, I, 2) --------------------
__global__ __launch_bounds__(256) void k_out(
    const float* __restrict__ X, const float* __restrict__ W, float* __restrict__ out)
{
  const int j = blockIdx.x;
  const int i = blockIdx.y * 256 + threadIdx.x;
  if (i >= I_DIM) return;
  const float2* __restrict__ X2 = (const float2*)X;
  float2 x0 = X2[(size_t)(0 * J_DIM + j) * I_DIM + i];
  float2 x1 = X2[(size_t)(1 * J_DIM + j) * I_DIM + i];
  const float4* __restrict__ W4 = (const float4*)W;
  float4 w0 = W4[i * 2 + 0];
  float4 w1 = W4[i * 2 + 1];
  float2* __restrict__ O = (float2*)out;
  float yr = w0.x * x0.x - w0.y * x0.y + w0.z * x1.x - w0.w * x1.y;
  float yi = w0.x * x0.y + w0.y * x0.x + w0.z * x1.y + w0.w * x1.x;
  O[(size_t)(0 * J_DIM + j) * I_DIM + i] = make_float2(yr, yi);
  yr = w1.x * x0.x - w1.y * x0.y + w1.z * x1.x - w1.w * x1.y;
  yi = w1.x * x0.y + w1.y * x0.x + w1.z * x1.y + w1.w * x1.x;
  O[(size_t)(1 * J_DIM + j) * I_DIM + i] = make_float2(yr, yi);
}

// ---------------- launch ----------------
extern "C" void kernel_launch(void* const* d_in, const int* in_sizes, int n_in,
                              void* d_out, int out_size, void* d_ws, size_t ws_size,
                              hipStream_t stream) {
  const float* X  = (const float*)d_in[0];   // (2, 2048, 1025, 2)
  const float* T0 = (const float*)d_in[1];   // (1025, 8, 2)
  const float* V0 = (const float*)d_in[2];   // (8, 2048, 2)
  float* ws = (float*)d_ws;
  // workspace layout (floats)
  float4* Xq  = (float4*)ws;           // 8396800 floats
  float* YdR0 = ws + 8396800;          // 2099200
  float* YdR1 = ws + 10496000;         // 2099200
  float* T    = ws + 12595200;         // 16400
  float* V    = ws + 12611600;         // 32768 ([n][j][k])
  float* W    = ws + 12644368;         // 8200
  float* Pn0  = ws + 12652568;         // 540672 ([c][j][k])
  float* Pd0  = ws + 13193240;         // 540672
  float* Pn1  = ws + 13733912;         // 540672
  float* Pd1  = ws + 14274584;         // 540672
  float* out  = (float*)d_out;

  k_tr_init<<<dim3(33, 64), dim3(32, 8), 0, stream>>>(X, Xq, T0, V0, T, V, W);
  k_nmfT<0><<<I_DIM, 256, 0, stream>>>(Xq, T, V, W, YdR0);           // A0
  for (int it = 0; it < 5; ++it) {
    // S2: part(0) [reads YdR0, T0 new] | nmfT(1) [writes YdR1, T1]
    k_s2<1, 0><<<264 + I_DIM, 256, 0, stream>>>(Xq, T, V, W, YdR1, YdR0, Pn0, Pd0);
    // S3: fin(0) [writes V0] | part(1) [reads YdR1, T1 new]
    k_s3<0, 1><<<64 + 264, 256, 0, stream>>>(V, Pn0, Pd0, T, YdR1, Pn1, Pd1);
    // S4: fin(1) [writes V1] | ip(0) [reads V0, T0; writes W row0]
    k_s4<0, 1><<<64 + I_DIM, 256, 0, stream>>>(Xq, T, V, W, Pn1, Pd1);
    if (it < 4) {
      // S1: ip(1) [reads V1, T1; writes W row1] | nmfT(0) next [writes YdR0, T0]
      k_s1<0, 1><<<2 * I_DIM, 256, 0, stream>>>(Xq, T, V, W, YdR0);
    } else {
      k_ip<1><<<I_DIM, 256, 0, stream>>>(Xq, T, V, W);               // D1 final
    }
  }
  k_out<<<dim3(J_DIM, 5), 256, 0, stream>>>(X, W, out);
}

// Round 8
// 292.810 us; speedup vs baseline: 4.5365x; 1.0703x over previous
//
#include <hip/hip_runtime.h>

#define I_DIM 1025
#define J_DIM 2048
#define K_B 8
#define IC 33            // i-chunks of 32 (last has 1)
#define EPSF 1e-20f

// ---------------- helpers ----------------

__device__ __forceinline__ int rev4i(int x) {
  return ((x & 1) << 3) | ((x & 2) << 1) | ((x & 4) >> 1) | ((x & 8) >> 3);
}
__device__ __forceinline__ int rev3i(int x) {
  return ((x & 1) << 2) | (x & 2) | ((x & 4) >> 2);
}

// value-halving butterfly: 16 vals over 64 lanes in 17 shuffles.
// Post: vals[0] of lane l (l<16) holds total of value rev4i(l).
__device__ __forceinline__ void foldReduce16(float* vals, int lane) {
  #pragma unroll
  for (int step = 0; step < 4; ++step) {
    const int nv = 8 >> step;           // 8,4,2,1
    const int bit = (lane >> step) & 1;
    #pragma unroll
    for (int q = 0; q < nv; ++q) {
      float a = vals[q], b = vals[q + nv];
      float send = bit ? a : b;
      float keep = bit ? b : a;
      vals[q] = keep + __shfl_xor(send, 1 << step);
    }
  }
  vals[0] += __shfl_xor(vals[0], 16);
  vals[0] += __shfl_xor(vals[0], 32);
}

// 8 vals over 64 lanes. Post: lane l (l<8) holds total of value rev3i(l).
__device__ __forceinline__ void foldReduce8(float* vals, int lane) {
  #pragma unroll
  for (int step = 0; step < 3; ++step) {
    const int nv = 4 >> step;           // 4,2,1
    const int bit = (lane >> step) & 1;
    #pragma unroll
    for (int q = 0; q < nv; ++q) {
      float a = vals[q], b = vals[q + nv];
      float send = bit ? a : b;
      float keep = bit ? b : a;
      vals[q] = keep + __shfl_xor(send, 1 << step);
    }
  }
  vals[0] += __shfl_xor(vals[0], 8);
  vals[0] += __shfl_xor(vals[0], 16);
  vals[0] += __shfl_xor(vals[0], 32);
}

__device__ __forceinline__ float2 cmul(float2 a, float2 b) {
  return make_float2(a.x*b.x - a.y*b.y, a.x*b.y + a.y*b.x);
}
__device__ __forceinline__ float2 cadd(float2 a, float2 b) {
  return make_float2(a.x + b.x, a.y + b.y);
}
__device__ __forceinline__ float2 csub(float2 a, float2 b) {
  return make_float2(a.x - b.x, a.y - b.y);
}
__device__ __forceinline__ float2 cdiv(float2 a, float2 b) {
  float s = 1.0f / (b.x*b.x + b.y*b.y);
  return make_float2((a.x*b.x + a.y*b.y)*s, (a.y*b.x - a.x*b.y)*s);
}

// ---------------- transpose X -> Xq[i][j]=(re0,im0,re1,im1), + init T/V/W ----
// T: [n][i][k]; V: [n][j][k] (float4-pair per j); W: [i][n][m][c]
__global__ __launch_bounds__(256) void k_tr_init(
    const float* __restrict__ X, float4* __restrict__ Xq,
    const float* __restrict__ T0, const float* __restrict__ V0,
    float* __restrict__ T, float* __restrict__ V, float* __restrict__ W)
{
  const int tx = threadIdx.x, ty = threadIdx.y;  // (32, 8)
  const int lt = ty * 32 + tx;
  const int bid = blockIdx.y * 33 + blockIdx.x;
  int t = bid * 256 + lt;
  if (t < 2 * K_B * J_DIM) {               // V: 32768, [n][j][k]
    int n = t >> 14;
    int r = t & 16383;
    int j = r >> 3, k = r & 7;
    V[t] = V0[(k * J_DIM + j) * 2 + n];
  }
  if (t < 2 * I_DIM * K_B) {               // T: 16400
    int n = t / (I_DIM * K_B);
    int r = t % (I_DIM * K_B);
    int i = r / K_B, k = r % K_B;
    T[t] = T0[(i * K_B + k) * 2 + n];
  }
  if (t < I_DIM * 8) {                     // W: 8200
    int u = t & 7;
    int c = u & 1, m = (u >> 1) & 1, n = u >> 2;
    W[t] = (n == m && c == 0) ? 1.0f : 0.0f;
  }
  // ---- transpose ----
  __shared__ float t0r[32][33], t0i[32][33], t1r[32][33], t1i[32][33];
  const int i0 = blockIdx.x * 32, j0 = blockIdx.y * 32;
  const float2* __restrict__ X2 = (const float2*)X;
  #pragma unroll
  for (int jj = 0; jj < 4; ++jj) {
    int jl = ty + jj * 8;
    int i = i0 + tx;
    if (i < I_DIM) {
      float2 v0 = X2[(size_t)(0 * J_DIM + j0 + jl) * I_DIM + i];
      float2 v1 = X2[(size_t)(1 * J_DIM + j0 + jl) * I_DIM + i];
      t0r[jl][tx] = v0.x; t0i[jl][tx] = v0.y;
      t1r[jl][tx] = v1.x; t1i[jl][tx] = v1.y;
    }
  }
  __syncthreads();
  #pragma unroll
  for (int ii = 0; ii < 4; ++ii) {
    int il = ty + ii * 8;
    int i = i0 + il;
    if (i < I_DIM) {
      Xq[(size_t)i * J_DIM + j0 + tx] =
        make_float4(t0r[tx][il], t0i[tx][il], t1r[tx][il], t1i[tx][il]);
    }
  }
}

// ---------------- NMF T-step body --------------------------------------------
template<int N>
__device__ __forceinline__ void nmfT_body(
    int i, int tid,
    const float4* __restrict__ Xq,
    float* __restrict__ T, const float* __restrict__ V,
    const float* __restrict__ W, float* __restrict__ YdR)
{
  float4 xs[8];
  #pragma unroll
  for (int u = 0; u < 8; ++u) xs[u] = Xq[(size_t)i * J_DIM + u * 256 + tid];

  const float4 w = ((const float4*)W)[i * 2 + N];
  float t[K_B];
  const int trow = (N * I_DIM + i) * K_B;
  #pragma unroll
  for (int k = 0; k < K_B; ++k) t[k] = T[trow + k];

  float num[K_B], den[K_B];
  #pragma unroll
  for (int k = 0; k < K_B; ++k) { num[k] = 0.f; den[k] = 0.f; }

  const float4* __restrict__ V4 = (const float4*)V;
  #pragma unroll
  for (int u = 0; u < 8; ++u) {
    int j = u * 256 + tid;
    float4 va = V4[(N * J_DIM + j) * 2 + 0];
    float4 vb = V4[(N * J_DIM + j) * 2 + 1];
    float v[K_B] = {va.x, va.y, va.z, va.w, vb.x, vb.y, vb.z, vb.w};
    float rn = 0.f;
    #pragma unroll
    for (int k = 0; k < K_B; ++k) rn += t[k] * v[k];
    float4 x = xs[u];
    float yr = w.x * x.x - w.y * x.y + w.z * x.z - w.w * x.w;
    float yi = w.x * x.y + w.y * x.x + w.z * x.w + w.w * x.z;
    float rd = 1.0f / (fabsf(rn) + EPSF);
    float ydr = (yr * yr + yi * yi) * rd * rd;
    YdR[(size_t)i * J_DIM + j] = ydr;
    #pragma unroll
    for (int k = 0; k < K_B; ++k) { num[k] += ydr * v[k]; den[k] += rd * v[k]; }
  }

  float vals[16];
  #pragma unroll
  for (int k = 0; k < K_B; ++k) { vals[k] = num[k]; vals[K_B + k] = den[k]; }
  const int wave = tid >> 6, lane = tid & 63;
  foldReduce16(vals, lane);
  __shared__ float redT[4][16];
  if (lane < 16) redT[wave][lane] = vals[0];   // slot l holds value rev4i(l)
  __syncthreads();
  if (tid < K_B) {
    int r = rev4i(tid);                        // value tid at slot r; tid+8 at r+1
    float nm = redT[0][r] + redT[1][r] + redT[2][r] + redT[3][r];
    float dn = redT[0][r+1] + redT[1][r+1] + redT[2][r+1] + redT[3][r+1];
    T[trow + tid] *= sqrtf(nm / (dn + EPSF));
  }
}

// ---------------- dual 2x2 solve epilogue (one thread, W in registers) -------
__device__ __forceinline__ void ip_solve_both(
    int i,
    float D000, float p0, float q0, float D110,
    float D001, float p1, float q1, float D111,
    float* __restrict__ W)
{
  float4 w0 = ((const float4*)W)[i * 2 + 0];
  float4 w1 = ((const float4*)W)[i * 2 + 1];
  float2 W00 = make_float2(w0.x, w0.y), W01 = make_float2(w0.z, w0.w);
  float2 W10 = make_float2(w1.x, w1.y), W11 = make_float2(w1.z, w1.w);
  // ---- n = 0 ----
  {
    float D00 = D000 + EPSF, D11 = D110 + EPSF;
    float2 D01 = make_float2(p0, q0);
    float2 D10 = make_float2(p0, -q0);
    float2 A00 = cadd(make_float2(W00.x * D00, W00.y * D00), cmul(W01, D10));
    float2 A01 = cadd(cmul(W00, D01), make_float2(W01.x * D11, W01.y * D11));
    float2 A10 = cadd(make_float2(W10.x * D00, W10.y * D00), cmul(W11, D10));
    float2 A11 = cadd(cmul(W10, D01), make_float2(W11.x * D11, W11.y * D11));
    float2 det = csub(cmul(A00, A11), cmul(A01, A10));
    float2 b0 = cdiv(A11, det);
    float2 b1 = cdiv(make_float2(-A10.x, -A10.y), det);
    float2 Db0 = cadd(make_float2(D00 * b0.x, D00 * b0.y), cmul(D01, b1));
    float2 Db1 = cadd(cmul(D10, b0), make_float2(D11 * b1.x, D11 * b1.y));
    float ip = b0.x * Db0.x + b0.y * Db0.y + b1.x * Db1.x + b1.y * Db1.y;
    float inv = 1.0f / sqrtf(ip + EPSF);
    W00 = make_float2(b0.x * inv, -b0.y * inv);
    W01 = make_float2(b1.x * inv, -b1.y * inv);
  }
  // ---- n = 1 ---- (uses the just-updated W00, W01)
  {
    float D00 = D001 + EPSF, D11 = D111 + EPSF;
    float2 D01 = make_float2(p1, q1);
    float2 D10 = make_float2(p1, -q1);
    float2 A00 = cadd(make_float2(W00.x * D00, W00.y * D00), cmul(W01, D10));
    float2 A01 = cadd(cmul(W00, D01), make_float2(W01.x * D11, W01.y * D11));
    float2 A10 = cadd(make_float2(W10.x * D00, W10.y * D00), cmul(W11, D10));
    float2 A11 = cadd(cmul(W10, D01), make_float2(W11.x * D11, W11.y * D11));
    float2 det = csub(cmul(A00, A11), cmul(A01, A10));
    float2 b0 = cdiv(make_float2(-A01.x, -A01.y), det);
    float2 b1 = cdiv(A00, det);
    float2 Db0 = cadd(make_float2(D00 * b0.x, D00 * b0.y), cmul(D01, b1));
    float2 Db1 = cadd(cmul(D10, b0), make_float2(D11 * b1.x, D11 * b1.y));
    float ip = b0.x * Db0.x + b0.y * Db0.y + b1.x * Db1.x + b1.y * Db1.y;
    float inv = 1.0f / sqrtf(ip + EPSF);
    W10 = make_float2(b0.x * inv, -b0.y * inv);
    W11 = make_float2(b1.x * inv, -b1.y * inv);
  }
  ((float4*)W)[i * 2 + 0] = make_float4(W00.x, W00.y, W01.x, W01.y);
  ((float4*)W)[i * 2 + 1] = make_float4(W10.x, W10.y, W11.x, W11.y);
}

// ---------------- V partials body --------------------------------------------
template<int N>
__device__ __forceinline__ void part_body(
    int pb, int tid,
    const float* __restrict__ T, const float* __restrict__ V,
    const float* __restrict__ YdR,
    float* __restrict__ Pn, float* __restrict__ Pd)
{
  const int jb = pb & 7;
  const int c  = pb >> 3;
  const int j  = jb * 256 + tid;
  const int i0 = c * 32;
  const int ni = min(32, I_DIM - i0);
  __shared__ float sT[32 * K_B];
  if (tid < ni * K_B) sT[tid] = T[(N * I_DIM + i0) * K_B + tid];
  __syncthreads();
  const float4* __restrict__ V4 = (const float4*)V;
  float4 va = V4[(N * J_DIM + j) * 2 + 0];
  float4 vb = V4[(N * J_DIM + j) * 2 + 1];
  float v[K_B] = {va.x, va.y, va.z, va.w, vb.x, vb.y, vb.z, vb.w};
  float num[K_B], den[K_B];
  #pragma unroll
  for (int k = 0; k < K_B; ++k) { num[k] = 0.f; den[k] = 0.f; }

  if (ni == 32) {
    #pragma unroll
    for (int g = 0; g < 4; ++g) {
      float yd[8];
      #pragma unroll
      for (int q = 0; q < 8; ++q)
        yd[q] = YdR[(size_t)(i0 + g * 8 + q) * J_DIM + j];
      #pragma unroll
      for (int q = 0; q < 8; ++q) {
        const int ii = g * 8 + q;
        float rn = 0.f;
        #pragma unroll
        for (int k = 0; k < K_B; ++k) rn += sT[ii * K_B + k] * v[k];
        float rd2 = 1.0f / (fabsf(rn) + EPSF);
        #pragma unroll
        for (int k = 0; k < K_B; ++k) {
          num[k] += sT[ii * K_B + k] * yd[q];
          den[k] += sT[ii * K_B + k] * rd2;
        }
      }
    }
  } else {
    for (int ii = 0; ii < ni; ++ii) {
      float ydr = YdR[(size_t)(i0 + ii) * J_DIM + j];
      float rn = 0.f;
      #pragma unroll
      for (int k = 0; k < K_B; ++k) rn += sT[ii * K_B + k] * v[k];
      float rd2 = 1.0f / (fabsf(rn) + EPSF);
      #pragma unroll
      for (int k = 0; k < K_B; ++k) {
        num[k] += sT[ii * K_B + k] * ydr;
        den[k] += sT[ii * K_B + k] * rd2;
      }
    }
  }
  // partials layout [c][j][k]
  ((float4*)Pn)[((size_t)c * J_DIM + j) * 2 + 0] = make_float4(num[0], num[1], num[2], num[3]);
  ((float4*)Pn)[((size_t)c * J_DIM + j) * 2 + 1] = make_float4(num[4], num[5], num[6], num[7]);
  ((float4*)Pd)[((size_t)c * J_DIM + j) * 2 + 0] = make_float4(den[0], den[1], den[2], den[3]);
  ((float4*)Pd)[((size_t)c * J_DIM + j) * 2 + 1] = make_float4(den[4], den[5], den[6], den[7]);
}

// ---------------- V finalize body --------------------------------------------
template<int N>
__device__ __forceinline__ void fin_body(
    int fb, int tid, float* __restrict__ V,
    const float* __restrict__ Pn, const float* __restrict__ Pd)
{
  const int t = fb * 256 + tid;   // (j,k): 16384 total
  float nm = 0.f, dn = 0.f;
  #pragma unroll
  for (int c = 0; c < IC; ++c) {
    nm += Pn[(size_t)c * (K_B * J_DIM) + t];
    dn += Pd[(size_t)c * (K_B * J_DIM) + t];
  }
  V[N * (K_B * J_DIM) + t] *= sqrtf(nm / (dn + EPSF));
}

// ---------------- K1: nmfT(0) | nmfT(1), XCD-paired on same X rows -----------
__global__ __launch_bounds__(256) void k_nmf2(
    const float4* __restrict__ Xq, float* __restrict__ T,
    const float* __restrict__ V, const float* __restrict__ W,
    float* __restrict__ YdR0, float* __restrict__ YdR1)
{
  int b = blockIdx.x;
  int p, pop;
  if (b >= 2048) { p = 1024; pop = b - 2048; }
  else { pop = (b >> 3) & 1; p = ((b >> 4) << 3) | (b & 7); }
  if (pop == 0)
    nmfT_body<0>(p, threadIdx.x, Xq, T, V, W, YdR0);
  else
    nmfT_body<1>(p, threadIdx.x, Xq, T, V, W, YdR1);
}

// ---------------- K2: part(0) | part(1) --------------------------------------
__global__ __launch_bounds__(256) void k_part2(
    const float* __restrict__ T, const float* __restrict__ V,
    const float* __restrict__ Y0, const float* __restrict__ Y1,
    float* __restrict__ Pn0, float* __restrict__ Pd0,
    float* __restrict__ Pn1, float* __restrict__ Pd1)
{
  if (blockIdx.x < 264)
    part_body<0>(blockIdx.x, threadIdx.x, T, V, Y0, Pn0, Pd0);
  else
    part_body<1>(blockIdx.x - 264, threadIdx.x, T, V, Y1, Pn1, Pd1);
}

// ---------------- K3: fin(0) | fin(1) ----------------------------------------
__global__ __launch_bounds__(256) void k_fin2(
    float* __restrict__ V,
    const float* __restrict__ Pn0, const float* __restrict__ Pd0,
    const float* __restrict__ Pn1, const float* __restrict__ Pd1)
{
  if (blockIdx.x < 64)
    fin_body<0>(blockIdx.x, threadIdx.x, V, Pn0, Pd0);
  else
    fin_body<1>(blockIdx.x - 64, threadIdx.x, V, Pn1, Pd1);
}

// ---------------- K4: ipBoth — one X pass, both D's, sequential solves -------
__global__ __launch_bounds__(256) void k_ip2(
    const float4* __restrict__ Xq, const float* __restrict__ T,
    const float* __restrict__ V, float* __restrict__ W)
{
  const int i = blockIdx.x;
  const int tid = threadIdx.x;
  float4 xs[8];
  #pragma unroll
  for (int u = 0; u < 8; ++u) xs[u] = Xq[(size_t)i * J_DIM + u * 256 + tid];

  float t0[K_B], t1[K_B];
  #pragma unroll
  for (int k = 0; k < K_B; ++k) {
    t0[k] = T[(0 * I_DIM + i) * K_B + k];
    t1[k] = T[(1 * I_DIM + i) * K_B + k];
  }
  const float4* __restrict__ V4 = (const float4*)V;
  float acc[8];   // d00_0, d01r_0, d01i_0, d11_0, d00_1, d01r_1, d01i_1, d11_1
  #pragma unroll
  for (int q = 0; q < 8; ++q) acc[q] = 0.f;

  #pragma unroll
  for (int u = 0; u < 8; ++u) {
    int j = u * 256 + tid;
    float4 va0 = V4[(0 * J_DIM + j) * 2 + 0];
    float4 vb0 = V4[(0 * J_DIM + j) * 2 + 1];
    float4 va1 = V4[(1 * J_DIM + j) * 2 + 0];
    float4 vb1 = V4[(1 * J_DIM + j) * 2 + 1];
    float rn0 = t0[0]*va0.x + t0[1]*va0.y + t0[2]*va0.z + t0[3]*va0.w
              + t0[4]*vb0.x + t0[5]*vb0.y + t0[6]*vb0.z + t0[7]*vb0.w;
    float rn1 = t1[0]*va1.x + t1[1]*va1.y + t1[2]*va1.z + t1[3]*va1.w
              + t1[4]*vb1.x + t1[5]*vb1.y + t1[6]*vb1.z + t1[7]*vb1.w;
    float w0 = 1.0f / (rn0 + EPSF);
    float w1 = 1.0f / (rn1 + EPSF);
    float4 x = xs[u];
    float m00 = x.x * x.x + x.y * x.y;
    float m11 = x.z * x.z + x.w * x.w;
    float m01r = x.x * x.z + x.y * x.w;
    float m01i = x.y * x.z - x.x * x.w;
    acc[0] += m00 * w0; acc[1] += m01r * w0; acc[2] += m01i * w0; acc[3] += m11 * w0;
    acc[4] += m00 * w1; acc[5] += m01r * w1; acc[6] += m01i * w1; acc[7] += m11 * w1;
  }
  const int wave = tid >> 6, lane = tid & 63;
  foldReduce8(acc, lane);
  __shared__ float red[4][8];
  if (lane < 8) red[wave][lane] = acc[0];    // slot l holds value rev3i(l)
  __syncthreads();
  if (tid == 0) {
    const float invJ = 1.0f / (float)J_DIM;
    float s[8];
    #pragma unroll
    for (int vv = 0; vv < 8; ++vv) {
      int r = rev3i(vv);
      s[vv] = (red[0][r] + red[1][r] + red[2][r] + red[3][r]) * invJ;
    }
    ip_solve_both(i, s[0], s[1], s[2], s[3], s[4], s[5], s[6], s[7], W);
  }
}

// ---------------- output: Y = W @ Xc, layout (N, J, I, 2) --------------------
__global__ __launch_bounds__(256) void k_out(
    const float* __restrict__ X, const float* __restrict__ W, float* __restrict__ out)
{
  const int j = blockIdx.x;
  const int i = blockIdx.y * 256 + threadIdx.x;
  if (i >= I_DIM) return;
  const float2* __restrict__ X2 = (const float2*)X;
  float2 x0 = X2[(size_t)(0 * J_DIM + j) * I_DIM + i];
  float2 x1 = X2[(size_t)(1 * J_DIM + j) * I_DIM + i];
  const float4* __restrict__ W4 = (const float4*)W;
  float4 w0 = W4[i * 2 + 0];
  float4 w1 = W4[i * 2 + 1];
  float2* __restrict__ O = (float2*)out;
  float yr = w0.x * x0.x - w0.y * x0.y + w0.z * x1.x - w0.w * x1.y;
  float yi = w0.x * x0.y + w0.y * x0.x + w0.z * x1.y + w0.w * x1.x;
  O[(size_t)(0 * J_DIM + j) * I_DIM + i] = make_float2(yr, yi);
  yr = w1.x * x0.x - w1.y * x0.y + w1.z * x1.x - w1.w * x1.y;
  yi = w1.x * x0.y + w1.y * x0.x + w1.z * x1.y + w1.w * x1.x;
  O[(size_t)(1 * J_DIM + j) * I_DIM + i] = make_float2(yr, yi);
}

// ---------------- launch ----------------
extern "C" void kernel_launch(void* const* d_in, const int* in_sizes, int n_in,
                              void* d_out, int out_size, void* d_ws, size_t ws_size,
                              hipStream_t stream) {
  const float* X  = (const float*)d_in[0];   // (2, 2048, 1025, 2)
  const float* T0 = (const float*)d_in[1];   // (1025, 8, 2)
  const float* V0 = (const float*)d_in[2];   // (8, 2048, 2)
  float* ws = (float*)d_ws;
  // workspace layout (floats)
  float4* Xq  = (float4*)ws;           // 8396800 floats
  float* YdR0 = ws + 8396800;          // 2099200
  float* YdR1 = ws + 10496000;         // 2099200
  float* T    = ws + 12595200;         // 16400
  float* V    = ws + 12611600;         // 32768 ([n][j][k])
  float* W    = ws + 12644368;         // 8200
  float* Pn0  = ws + 12652568;         // 540672 ([c][j][k])
  float* Pd0  = ws + 13193240;         // 540672
  float* Pn1  = ws + 13733912;         // 540672
  float* Pd1  = ws + 14274584;         // 540672
  float* out  = (float*)d_out;

  k_tr_init<<<dim3(33, 64), dim3(32, 8), 0, stream>>>(X, Xq, T0, V0, T, V, W);
  for (int it = 0; it < 5; ++it) {
    k_nmf2<<<2 * I_DIM, 256, 0, stream>>>(Xq, T, V, W, YdR0, YdR1);
    k_part2<<<2 * 264, 256, 0, stream>>>(T, V, YdR0, YdR1, Pn0, Pd0, Pn1, Pd1);
    k_fin2<<<2 * 64, 256, 0, stream>>>(V, Pn0, Pd0, Pn1, Pd1);
    k_ip2<<<I_DIM, 256, 0, stream>>>(Xq, T, V, W);
  }
  k_out<<<dim3(J_DIM, 5), 256, 0, stream>>>(X, W, out);
}

// Round 9
// 289.792 us; speedup vs baseline: 4.5838x; 1.0104x over previous
//
#include <hip/hip_runtime.h>

#define I_DIM 1025
#define J_DIM 2048
#define K_B 8
#define IC 33            // i-chunks of 32 (last has 1)
#define EPSF 1e-20f

typedef float vf2 __attribute__((ext_vector_type(2)));

// ---------------- helpers ----------------

__device__ __forceinline__ int rev4i(int x) {
  return ((x & 1) << 3) | ((x & 2) << 1) | ((x & 4) >> 1) | ((x & 8) >> 3);
}
__device__ __forceinline__ int rev3i(int x) {
  return ((x & 1) << 2) | (x & 2) | ((x & 4) >> 2);
}

// value-halving butterfly: 16 vals over 64 lanes in 17 shuffles.
// Post: vals[0] of lane l (l<16) holds total of value rev4i(l).
__device__ __forceinline__ void foldReduce16(float* vals, int lane) {
  #pragma unroll
  for (int step = 0; step < 4; ++step) {
    const int nv = 8 >> step;           // 8,4,2,1
    const int bit = (lane >> step) & 1;
    #pragma unroll
    for (int q = 0; q < nv; ++q) {
      float a = vals[q], b = vals[q + nv];
      float send = bit ? a : b;
      float keep = bit ? b : a;
      vals[q] = keep + __shfl_xor(send, 1 << step);
    }
  }
  vals[0] += __shfl_xor(vals[0], 16);
  vals[0] += __shfl_xor(vals[0], 32);
}

// 8 vals over 64 lanes. Post: lane l (l<8) holds total of value rev3i(l).
__device__ __forceinline__ void foldReduce8(float* vals, int lane) {
  #pragma unroll
  for (int step = 0; step < 3; ++step) {
    const int nv = 4 >> step;           // 4,2,1
    const int bit = (lane >> step) & 1;
    #pragma unroll
    for (int q = 0; q < nv; ++q) {
      float a = vals[q], b = vals[q + nv];
      float send = bit ? a : b;
      float keep = bit ? b : a;
      vals[q] = keep + __shfl_xor(send, 1 << step);
    }
  }
  vals[0] += __shfl_xor(vals[0], 8);
  vals[0] += __shfl_xor(vals[0], 16);
  vals[0] += __shfl_xor(vals[0], 32);
}

__device__ __forceinline__ float2 cmul(float2 a, float2 b) {
  return make_float2(a.x*b.x - a.y*b.y, a.x*b.y + a.y*b.x);
}
__device__ __forceinline__ float2 cadd(float2 a, float2 b) {
  return make_float2(a.x + b.x, a.y + b.y);
}
__device__ __forceinline__ float2 csub(float2 a, float2 b) {
  return make_float2(a.x - b.x, a.y - b.y);
}
__device__ __forceinline__ float2 cdiv(float2 a, float2 b) {
  float s = 1.0f / (b.x*b.x + b.y*b.y);
  return make_float2((a.x*b.x + a.y*b.y)*s, (a.y*b.x - a.x*b.y)*s);
}

// ---------------- transpose X -> Xq[i][j]=(re0,im0,re1,im1), + init T/V/W ----
// T: [n][i][k]; V: [n][j][k] (float4-pair per j); W: [i][n][m][c]
__global__ __launch_bounds__(256) void k_tr_init(
    const float* __restrict__ X, float4* __restrict__ Xq,
    const float* __restrict__ T0, const float* __restrict__ V0,
    float* __restrict__ T, float* __restrict__ V, float* __restrict__ W)
{
  const int tx = threadIdx.x, ty = threadIdx.y;  // (32, 8)
  const int lt = ty * 32 + tx;
  const int bid = blockIdx.y * 33 + blockIdx.x;
  int t = bid * 256 + lt;
  if (t < 2 * K_B * J_DIM) {               // V: 32768, [n][j][k]
    int n = t >> 14;
    int r = t & 16383;
    int j = r >> 3, k = r & 7;
    V[t] = V0[(k * J_DIM + j) * 2 + n];
  }
  if (t < 2 * I_DIM * K_B) {               // T: 16400
    int n = t / (I_DIM * K_B);
    int r = t % (I_DIM * K_B);
    int i = r / K_B, k = r % K_B;
    T[t] = T0[(i * K_B + k) * 2 + n];
  }
  if (t < I_DIM * 8) {                     // W: 8200
    int u = t & 7;
    int c = u & 1, m = (u >> 1) & 1, n = u >> 2;
    W[t] = (n == m && c == 0) ? 1.0f : 0.0f;
  }
  // ---- transpose ----
  __shared__ float t0r[32][33], t0i[32][33], t1r[32][33], t1i[32][33];
  const int i0 = blockIdx.x * 32, j0 = blockIdx.y * 32;
  const float2* __restrict__ X2 = (const float2*)X;
  #pragma unroll
  for (int jj = 0; jj < 4; ++jj) {
    int jl = ty + jj * 8;
    int i = i0 + tx;
    if (i < I_DIM) {
      float2 v0 = X2[(size_t)(0 * J_DIM + j0 + jl) * I_DIM + i];
      float2 v1 = X2[(size_t)(1 * J_DIM + j0 + jl) * I_DIM + i];
      t0r[jl][tx] = v0.x; t0i[jl][tx] = v0.y;
      t1r[jl][tx] = v1.x; t1i[jl][tx] = v1.y;
    }
  }
  __syncthreads();
  #pragma unroll
  for (int ii = 0; ii < 4; ++ii) {
    int il = ty + ii * 8;
    int i = i0 + il;
    if (i < I_DIM) {
      Xq[(size_t)i * J_DIM + j0 + tx] =
        make_float4(t0r[tx][il], t0i[tx][il], t1r[tx][il], t1i[tx][il]);
    }
  }
}

// ---------------- NMF T-step body (packed fp32) ------------------------------
template<int N>
__device__ __forceinline__ void nmfT_body(
    int i, int tid,
    const float4* __restrict__ Xq,
    float* __restrict__ T, const float* __restrict__ V,
    const float* __restrict__ W, float* __restrict__ YdR)
{
  float4 xs[8];
  #pragma unroll
  for (int u = 0; u < 8; ++u) xs[u] = Xq[(size_t)i * J_DIM + u * 256 + tid];

  const float4 w = ((const float4*)W)[i * 2 + N];
  const int trow = (N * I_DIM + i) * K_B;
  vf2 t2[4];
  #pragma unroll
  for (int q = 0; q < 4; ++q) t2[q] = vf2{T[trow + 2*q], T[trow + 2*q + 1]};

  vf2 num2[4], den2[4];
  #pragma unroll
  for (int q = 0; q < 4; ++q) { num2[q] = vf2{0.f,0.f}; den2[q] = vf2{0.f,0.f}; }

  const float4* __restrict__ V4 = (const float4*)V;
  #pragma unroll
  for (int u = 0; u < 8; ++u) {
    int j = u * 256 + tid;
    float4 va = V4[(N * J_DIM + j) * 2 + 0];
    float4 vb = V4[(N * J_DIM + j) * 2 + 1];
    vf2 v2[4] = {vf2{va.x,va.y}, vf2{va.z,va.w}, vf2{vb.x,vb.y}, vf2{vb.z,vb.w}};
    vf2 rn2 = t2[0]*v2[0] + t2[1]*v2[1] + t2[2]*v2[2] + t2[3]*v2[3];
    float rn = rn2.x + rn2.y;
    float4 x = xs[u];
    float yr = w.x * x.x - w.y * x.y + w.z * x.z - w.w * x.w;
    float yi = w.x * x.y + w.y * x.x + w.z * x.w + w.w * x.z;
    float rd = __builtin_amdgcn_rcpf(fabsf(rn) + EPSF);
    float ydr = (yr * yr + yi * yi) * rd * rd;
    YdR[(size_t)i * J_DIM + j] = ydr;
    vf2 ydr2 = vf2{ydr, ydr};
    vf2 rdv2 = vf2{rd, rd};
    #pragma unroll
    for (int q = 0; q < 4; ++q) { num2[q] += ydr2 * v2[q]; den2[q] += rdv2 * v2[q]; }
  }

  float vals[16];
  #pragma unroll
  for (int q = 0; q < 4; ++q) {
    vals[2*q] = num2[q].x;   vals[2*q+1] = num2[q].y;
    vals[8+2*q] = den2[q].x; vals[8+2*q+1] = den2[q].y;
  }
  const int wave = tid >> 6, lane = tid & 63;
  foldReduce16(vals, lane);
  __shared__ float redT[4][16];
  if (lane < 16) redT[wave][lane] = vals[0];   // slot l holds value rev4i(l)
  __syncthreads();
  if (tid < K_B) {
    int r = rev4i(tid);                        // value tid at slot r; tid+8 at r+1
    float nm = redT[0][r] + redT[1][r] + redT[2][r] + redT[3][r];
    float dn = redT[0][r+1] + redT[1][r+1] + redT[2][r+1] + redT[3][r+1];
    T[trow + tid] *= sqrtf(nm / (dn + EPSF));
  }
}

// ---------------- dual 2x2 solve epilogue (one thread, W in registers) -------
__device__ __forceinline__ void ip_solve_both(
    int i,
    float D000, float p0, float q0, float D110,
    float D001, float p1, float q1, float D111,
    float* __restrict__ W)
{
  float4 w0 = ((const float4*)W)[i * 2 + 0];
  float4 w1 = ((const float4*)W)[i * 2 + 1];
  float2 W00 = make_float2(w0.x, w0.y), W01 = make_float2(w0.z, w0.w);
  float2 W10 = make_float2(w1.x, w1.y), W11 = make_float2(w1.z, w1.w);
  // ---- n = 0 ----
  {
    float D00 = D000 + EPSF, D11 = D110 + EPSF;
    float2 D01 = make_float2(p0, q0);
    float2 D10 = make_float2(p0, -q0);
    float2 A00 = cadd(make_float2(W00.x * D00, W00.y * D00), cmul(W01, D10));
    float2 A01 = cadd(cmul(W00, D01), make_float2(W01.x * D11, W01.y * D11));
    float2 A10 = cadd(make_float2(W10.x * D00, W10.y * D00), cmul(W11, D10));
    float2 A11 = cadd(cmul(W10, D01), make_float2(W11.x * D11, W11.y * D11));
    float2 det = csub(cmul(A00, A11), cmul(A01, A10));
    float2 b0 = cdiv(A11, det);
    float2 b1 = cdiv(make_float2(-A10.x, -A10.y), det);
    float2 Db0 = cadd(make_float2(D00 * b0.x, D00 * b0.y), cmul(D01, b1));
    float2 Db1 = cadd(cmul(D10, b0), make_float2(D11 * b1.x, D11 * b1.y));
    float ip = b0.x * Db0.x + b0.y * Db0.y + b1.x * Db1.x + b1.y * Db1.y;
    float inv = 1.0f / sqrtf(ip + EPSF);
    W00 = make_float2(b0.x * inv, -b0.y * inv);
    W01 = make_float2(b1.x * inv, -b1.y * inv);
  }
  // ---- n = 1 ---- (uses the just-updated W00, W01)
  {
    float D00 = D001 + EPSF, D11 = D111 + EPSF;
    float2 D01 = make_float2(p1, q1);
    float2 D10 = make_float2(p1, -q1);
    float2 A00 = cadd(make_float2(W00.x * D00, W00.y * D00), cmul(W01, D10));
    float2 A01 = cadd(cmul(W00, D01), make_float2(W01.x * D11, W01.y * D11));
    float2 A10 = cadd(make_float2(W10.x * D00, W10.y * D00), cmul(W11, D10));
    float2 A11 = cadd(cmul(W10, D01), make_float2(W11.x * D11, W11.y * D11));
    float2 det = csub(cmul(A00, A11), cmul(A01, A10));
    float2 b0 = cdiv(make_float2(-A01.x, -A01.y), det);
    float2 b1 = cdiv(A00, det);
    float2 Db0 = cadd(make_float2(D00 * b0.x, D00 * b0.y), cmul(D01, b1));
    float2 Db1 = cadd(cmul(D10, b0), make_float2(D11 * b1.x, D11 * b1.y));
    float ip = b0.x * Db0.x + b0.y * Db0.y + b1.x * Db1.x + b1.y * Db1.y;
    float inv = 1.0f / sqrtf(ip + EPSF);
    W10 = make_float2(b0.x * inv, -b0.y * inv);
    W11 = make_float2(b1.x * inv, -b1.y * inv);
  }
  ((float4*)W)[i * 2 + 0] = make_float4(W00.x, W00.y, W01.x, W01.y);
  ((float4*)W)[i * 2 + 1] = make_float4(W10.x, W10.y, W11.x, W11.y);
}

// ---------------- V partials body (packed fp32, b128 LDS) --------------------
template<int N>
__device__ __forceinline__ void part_body(
    int pb, int tid,
    const float* __restrict__ T, const float* __restrict__ V,
    const float* __restrict__ YdR,
    float* __restrict__ Pn, float* __restrict__ Pd)
{
  const int jb = pb & 7;
  const int c  = pb >> 3;
  const int j  = jb * 256 + tid;
  const int i0 = c * 32;
  const int ni = min(32, I_DIM - i0);
  __shared__ float4 sT4[32 * 2];
  if (tid < ni * 2) sT4[tid] = ((const float4*)(T + (size_t)(N * I_DIM + i0) * K_B))[tid];
  __syncthreads();
  const float4* __restrict__ V4 = (const float4*)V;
  float4 va = V4[(N * J_DIM + j) * 2 + 0];
  float4 vb = V4[(N * J_DIM + j) * 2 + 1];
  vf2 v2[4] = {vf2{va.x,va.y}, vf2{va.z,va.w}, vf2{vb.x,vb.y}, vf2{vb.z,vb.w}};
  vf2 num2[4], den2[4];
  #pragma unroll
  for (int q = 0; q < 4; ++q) { num2[q] = vf2{0.f,0.f}; den2[q] = vf2{0.f,0.f}; }

  if (ni == 32) {
    #pragma unroll
    for (int g = 0; g < 4; ++g) {
      float yd[8];
      #pragma unroll
      for (int q = 0; q < 8; ++q)
        yd[q] = YdR[(size_t)(i0 + g * 8 + q) * J_DIM + j];
      #pragma unroll
      for (int q = 0; q < 8; ++q) {
        const int ii = g * 8 + q;
        float4 ta = sT4[ii * 2], tb = sT4[ii * 2 + 1];
        vf2 t2[4] = {vf2{ta.x,ta.y}, vf2{ta.z,ta.w}, vf2{tb.x,tb.y}, vf2{tb.z,tb.w}};
        vf2 rn2 = t2[0]*v2[0] + t2[1]*v2[1] + t2[2]*v2[2] + t2[3]*v2[3];
        float rd2 = __builtin_amdgcn_rcpf(fabsf(rn2.x + rn2.y) + EPSF);
        vf2 yd2 = vf2{yd[q], yd[q]};
        vf2 rdv = vf2{rd2, rd2};
        #pragma unroll
        for (int k = 0; k < 4; ++k) {
          num2[k] += t2[k] * yd2;
          den2[k] += t2[k] * rdv;
        }
      }
    }
  } else {
    for (int ii = 0; ii < ni; ++ii) {
      float ydr = YdR[(size_t)(i0 + ii) * J_DIM + j];
      float4 ta = sT4[ii * 2], tb = sT4[ii * 2 + 1];
      vf2 t2[4] = {vf2{ta.x,ta.y}, vf2{ta.z,ta.w}, vf2{tb.x,tb.y}, vf2{tb.z,tb.w}};
      vf2 rn2 = t2[0]*v2[0] + t2[1]*v2[1] + t2[2]*v2[2] + t2[3]*v2[3];
      float rd2 = __builtin_amdgcn_rcpf(fabsf(rn2.x + rn2.y) + EPSF);
      vf2 yd2 = vf2{ydr, ydr};
      vf2 rdv = vf2{rd2, rd2};
      #pragma unroll
      for (int k = 0; k < 4; ++k) {
        num2[k] += t2[k] * yd2;
        den2[k] += t2[k] * rdv;
      }
    }
  }
  // partials layout [c][j][k]
  ((float4*)Pn)[((size_t)c * J_DIM + j) * 2 + 0] = make_float4(num2[0].x, num2[0].y, num2[1].x, num2[1].y);
  ((float4*)Pn)[((size_t)c * J_DIM + j) * 2 + 1] = make_float4(num2[2].x, num2[2].y, num2[3].x, num2[3].y);
  ((float4*)Pd)[((size_t)c * J_DIM + j) * 2 + 0] = make_float4(den2[0].x, den2[0].y, den2[1].x, den2[1].y);
  ((float4*)Pd)[((size_t)c * J_DIM + j) * 2 + 1] = make_float4(den2[2].x, den2[2].y, den2[3].x, den2[3].y);
}

// ---------------- V finalize body (float4) -----------------------------------
template<int N>
__device__ __forceinline__ void fin_body(
    int fb, int tid, float* __restrict__ V,
    const float* __restrict__ Pn, const float* __restrict__ Pd)
{
  const int t4 = fb * 256 + tid;  // float4 index, 4096 total per source
  const float4* __restrict__ Pn4 = (const float4*)Pn;
  const float4* __restrict__ Pd4 = (const float4*)Pd;
  float4 nm = make_float4(0.f, 0.f, 0.f, 0.f);
  float4 dn = make_float4(0.f, 0.f, 0.f, 0.f);
  #pragma unroll
  for (int c = 0; c < IC; ++c) {
    float4 a = Pn4[(size_t)c * 4096 + t4];
    float4 b = Pd4[(size_t)c * 4096 + t4];
    nm.x += a.x; nm.y += a.y; nm.z += a.z; nm.w += a.w;
    dn.x += b.x; dn.y += b.y; dn.z += b.z; dn.w += b.w;
  }
  float4* __restrict__ V4o = (float4*)(V + N * (K_B * J_DIM));
  float4 v = V4o[t4];
  v.x *= sqrtf(nm.x / (dn.x + EPSF));
  v.y *= sqrtf(nm.y / (dn.y + EPSF));
  v.z *= sqrtf(nm.z / (dn.z + EPSF));
  v.w *= sqrtf(nm.w / (dn.w + EPSF));
  V4o[t4] = v;
}

// ---------------- K1: nmfT(0) | nmfT(1), XCD-paired on same X rows -----------
__global__ __launch_bounds__(256) void k_nmf2(
    const float4* __restrict__ Xq, float* __restrict__ T,
    const float* __restrict__ V, const float* __restrict__ W,
    float* __restrict__ YdR0, float* __restrict__ YdR1)
{
  int b = blockIdx.x;
  int p, pop;
  if (b >= 2048) { p = 1024; pop = b - 2048; }
  else { pop = (b >> 3) & 1; p = ((b >> 4) << 3) | (b & 7); }
  if (pop == 0)
    nmfT_body<0>(p, threadIdx.x, Xq, T, V, W, YdR0);
  else
    nmfT_body<1>(p, threadIdx.x, Xq, T, V, W, YdR1);
}

// ---------------- K2: part(0) | part(1) --------------------------------------
__global__ __launch_bounds__(256) void k_part2(
    const float* __restrict__ T, const float* __restrict__ V,
    const float* __restrict__ Y0, const float* __restrict__ Y1,
    float* __restrict__ Pn0, float* __restrict__ Pd0,
    float* __restrict__ Pn1, float* __restrict__ Pd1)
{
  if (blockIdx.x < 264)
    part_body<0>(blockIdx.x, threadIdx.x, T, V, Y0, Pn0, Pd0);
  else
    part_body<1>(blockIdx.x - 264, threadIdx.x, T, V, Y1, Pn1, Pd1);
}

// ---------------- K3: fin(0) | fin(1) ----------------------------------------
__global__ __launch_bounds__(256) void k_fin2(
    float* __restrict__ V,
    const float* __restrict__ Pn0, const float* __restrict__ Pd0,
    const float* __restrict__ Pn1, const float* __restrict__ Pd1)
{
  if (blockIdx.x < 16)
    fin_body<0>(blockIdx.x, threadIdx.x, V, Pn0, Pd0);
  else
    fin_body<1>(blockIdx.x - 16, threadIdx.x, V, Pn1, Pd1);
}

// ---------------- K4: ipBoth — one X pass, both D's, sequential solves -------
__global__ __launch_bounds__(256) void k_ip2(
    const float4* __restrict__ Xq, const float* __restrict__ T,
    const float* __restrict__ V, float* __restrict__ W)
{
  const int i = blockIdx.x;
  const int tid = threadIdx.x;
  float4 xs[8];
  #pragma unroll
  for (int u = 0; u < 8; ++u) xs[u] = Xq[(size_t)i * J_DIM + u * 256 + tid];

  vf2 t0_2[4], t1_2[4];
  #pragma unroll
  for (int q = 0; q < 4; ++q) {
    t0_2[q] = vf2{T[(0 * I_DIM + i) * K_B + 2*q], T[(0 * I_DIM + i) * K_B + 2*q + 1]};
    t1_2[q] = vf2{T[(1 * I_DIM + i) * K_B + 2*q], T[(1 * I_DIM + i) * K_B + 2*q + 1]};
  }
  const float4* __restrict__ V4 = (const float4*)V;
  // acc2[0]={d00_0,d01r_0} acc2[1]={d01i_0,d11_0} acc2[2..3] same for n=1
  vf2 acc2[4];
  #pragma unroll
  for (int q = 0; q < 4; ++q) acc2[q] = vf2{0.f, 0.f};

  #pragma unroll
  for (int u = 0; u < 8; ++u) {
    int j = u * 256 + tid;
    float4 va0 = V4[(0 * J_DIM + j) * 2 + 0];
    float4 vb0 = V4[(0 * J_DIM + j) * 2 + 1];
    float4 va1 = V4[(1 * J_DIM + j) * 2 + 0];
    float4 vb1 = V4[(1 * J_DIM + j) * 2 + 1];
    vf2 r0 = t0_2[0]*vf2{va0.x,va0.y} + t0_2[1]*vf2{va0.z,va0.w}
           + t0_2[2]*vf2{vb0.x,vb0.y} + t0_2[3]*vf2{vb0.z,vb0.w};
    vf2 r1 = t1_2[0]*vf2{va1.x,va1.y} + t1_2[1]*vf2{va1.z,va1.w}
           + t1_2[2]*vf2{vb1.x,vb1.y} + t1_2[3]*vf2{vb1.z,vb1.w};
    float w0 = __builtin_amdgcn_rcpf(r0.x + r0.y + EPSF);
    float w1 = __builtin_amdgcn_rcpf(r1.x + r1.y + EPSF);
    float4 x = xs[u];
    // {m00, m01r} and {m01i, m11} via packed fma
    vf2 mA = vf2{x.x, x.x} * vf2{x.x, x.z} + vf2{x.y, x.y} * vf2{x.y, x.w};
    vf2 mB = vf2{x.y, x.z} * vf2{x.z, x.z} + vf2{-x.x, x.w} * vf2{x.w, x.w};
    acc2[0] += mA * vf2{w0, w0};
    acc2[1] += mB * vf2{w0, w0};
    acc2[2] += mA * vf2{w1, w1};
    acc2[3] += mB * vf2{w1, w1};
  }
  float acc[8] = {acc2[0].x, acc2[0].y, acc2[1].x, acc2[1].y,
                  acc2[2].x, acc2[2].y, acc2[3].x, acc2[3].y};
  const int wave = tid >> 6, lane = tid & 63;
  foldReduce8(acc, lane);
  __shared__ float red[4][8];
  if (lane < 8) red[wave][lane] = acc[0];    // slot l holds value rev3i(l)
  __syncthreads();
  if (tid == 0) {
    const float invJ = 1.0f / (float)J_DIM;
    float s[8];
    #pragma unroll
    for (int vv = 0; vv < 8; ++vv) {
      int r = rev3i(vv);
      s[vv] = (red[0][r] + red[1][r] + red[2][r] + red[3][r]) * invJ;
    }
    ip_solve_both(i, s[0], s[1], s[2], s[3], s[4], s[5], s[6], s[7], W);
  }
}

// ---------------- output: Y = W @ Xc, layout (N, J, I, 2) --------------------
__global__ __launch_bounds__(256) void k_out(
    const float* __restrict__ X, const float* __restrict__ W, float* __restrict__ out)
{
  const int j = blockIdx.x;
  const int i = blockIdx.y * 256 + threadIdx.x;
  if (i >= I_DIM) return;
  const float2* __restrict__ X2 = (const float2*)X;
  float2 x0 = X2[(size_t)(0 * J_DIM + j) * I_DIM + i];
  float2 x1 = X2[(size_t)(1 * J_DIM + j) * I_DIM + i];
  const float4* __restrict__ W4 = (const float4*)W;
  float4 w0 = W4[i * 2 + 0];
  float4 w1 = W4[i * 2 + 1];
  float2* __restrict__ O = (float2*)out;
  float yr = w0.x * x0.x - w0.y * x0.y + w0.z * x1.x - w0.w * x1.y;
  float yi = w0.x * x0.y + w0.y * x0.x + w0.z * x1.y + w0.w * x1.x;
  O[(size_t)(0 * J_DIM + j) * I_DIM + i] = make_float2(yr, yi);
  yr = w1.x * x0.x - w1.y * x0.y + w1.z * x1.x - w1.w * x1.y;
  yi = w1.x * x0.y + w1.y * x0.x + w1.z * x1.y + w1.w * x1.x;
  O[(size_t)(1 * J_DIM + j) * I_DIM + i] = make_float2(yr, yi);
}

// ---------------- launch ----------------
extern "C" void kernel_launch(void* const* d_in, const int* in_sizes, int n_in,
                              void* d_out, int out_size, void* d_ws, size_t ws_size,
                              hipStream_t stream) {
  const float* X  = (const float*)d_in[0];   // (2, 2048, 1025, 2)
  const float* T0 = (const float*)d_in[1];   // (1025, 8, 2)
  const float* V0 = (const float*)d_in[2];   // (8, 2048, 2)
  float* ws = (float*)d_ws;
  // workspace layout (floats)
  float4* Xq  = (float4*)ws;           // 8396800 floats
  float* YdR0 = ws + 8396800;          // 2099200
  float* YdR1 = ws + 10496000;         // 2099200
  float* T    = ws + 12595200;         // 16400
  float* V    = ws + 12611600;         // 32768 ([n][j][k])
  float* W    = ws + 12644368;         // 8200
  float* Pn0  = ws + 12652568;         // 540672 ([c][j][k])
  float* Pd0  = ws + 13193240;         // 540672
  float* Pn1  = ws + 13733912;         // 540672
  float* Pd1  = ws + 14274584;         // 540672
  float* out  = (float*)d_out;

  k_tr_init<<<dim3(33, 64), dim3(32, 8), 0, stream>>>(X, Xq, T0, V0, T, V, W);
  for (int it = 0; it < 5; ++it) {
    k_nmf2<<<2 * I_DIM, 256, 0, stream>>>(Xq, T, V, W, YdR0, YdR1);
    k_part2<<<2 * 264, 256, 0, stream>>>(T, V, YdR0, YdR1, Pn0, Pd0, Pn1, Pd1);
    k_fin2<<<2 * 16, 256, 0, stream>>>(V, Pn0, Pd0, Pn1, Pd1);
    k_ip2<<<I_DIM, 256, 0, stream>>>(Xq, T, V, W);
  }
  k_out<<<dim3(J_DIM, 5), 256, 0, stream>>>(X, W, out);
}